// Round 14
// baseline (1240.745 us; speedup 1.0000x reference)
//
#include <hip/hip_runtime.h>
#include <hip/hip_bf16.h>
#include <math.h>

#define B_ 32
#define S_ 512
#define D_ 512
#define H_ 8
#define DK_ 64
#define DFF_ 2048
#define L_ 4

typedef __attribute__((ext_vector_type(8))) short bf16x8;
typedef __attribute__((ext_vector_type(4))) float f32x4;

__device__ __forceinline__ unsigned short f2bf(float x) {
  union { float f; unsigned u; } v; v.f = x;
  unsigned r = v.u + 0x7fff + ((v.u >> 16) & 1);   // round-nearest-even
  return (unsigned short)(r >> 16);
}

__device__ __forceinline__ unsigned short f2h(float x) {
  union { _Float16 h; unsigned short u; } v;
  v.h = (_Float16)x;
  return v.u;
}
__device__ __forceinline__ float h2f(unsigned short u) {
  union { _Float16 h; unsigned short u; } v;
  v.u = u;
  return (float)v.h;
}

// inclusive 16-lane prefix sum via DPP row_shr (VALU only). bound_ctrl -> 0-fill.
#define DPP_ADD_SHR(x, N)                                                       \
  {                                                                             \
    int _t = __builtin_amdgcn_update_dpp(0, __float_as_int(x), 0x110 + (N),     \
                                         0xf, 0xf, true);                       \
    (x) += __int_as_float(_t);                                                  \
  }
__device__ __forceinline__ float scan16_dpp(float x) {
  DPP_ADD_SHR(x, 1);
  DPP_ADD_SHR(x, 2);
  DPP_ADD_SHR(x, 4);
  DPP_ADD_SHR(x, 8);
  return x;
}
// broadcast lane (id|15)'s value to all lanes of each 16-lane row
__device__ __forceinline__ float bcast15(float x) {
  return __int_as_float(__builtin_amdgcn_ds_swizzle(__float_as_int(x), 0x1FF));
}

__device__ __forceinline__ void load_lds16(const void* g, void* l) {
  __builtin_amdgcn_global_load_lds(
      (const __attribute__((address_space(1))) void*)g,
      (__attribute__((address_space(3))) void*)l, 16, 0, 0);
}

// ---------- f32 -> bf16 convert ----------
__global__ __launch_bounds__(256) void cvt_f32_bf16(
    const float* __restrict__ in, unsigned short* __restrict__ out, size_t n8)
{
  size_t idx = (size_t)blockIdx.x * 256 + threadIdx.x;
  size_t stride = (size_t)gridDim.x * 256;
  for (size_t i = idx; i < n8; i += stride) {
    const float4* p = (const float4*)(in + i * 8);
    float4 a = p[0], b = p[1];
    union { unsigned short u[8]; int4 v; } o;
    o.u[0] = f2bf(a.x); o.u[1] = f2bf(a.y); o.u[2] = f2bf(a.z); o.u[3] = f2bf(a.w);
    o.u[4] = f2bf(b.x); o.u[5] = f2bf(b.y); o.u[6] = f2bf(b.z); o.u[7] = f2bf(b.w);
    *(int4*)(out + i * 8) = o.v;
  }
}

// ---------- copy f32 + emit bf16 ----------
__global__ __launch_bounds__(256) void copy_cvt(
    const float* __restrict__ in, float* __restrict__ outf,
    unsigned short* __restrict__ outb, size_t n8)
{
  size_t idx = (size_t)blockIdx.x * 256 + threadIdx.x;
  size_t stride = (size_t)gridDim.x * 256;
  for (size_t i = idx; i < n8; i += stride) {
    const float4* p = (const float4*)(in + i * 8);
    float4 a = p[0], b = p[1];
    ((float4*)(outf + i * 8))[0] = a;
    ((float4*)(outf + i * 8))[1] = b;
    union { unsigned short u[8]; int4 v; } o;
    o.u[0] = f2bf(a.x); o.u[1] = f2bf(a.y); o.u[2] = f2bf(a.z); o.u[3] = f2bf(a.w);
    o.u[4] = f2bf(b.x); o.u[5] = f2bf(b.y); o.u[6] = f2bf(b.z); o.u[7] = f2bf(b.w);
    *(int4*)(outb + i * 8) = o.v;
  }
}

// ---------- bf16 MFMA GEMM: C[M,N] = A[M,K] @ W[N,K]^T + bias ----------
__global__ __launch_bounds__(256) void gemm_bt_bf16(
    const unsigned short* __restrict__ A, const unsigned short* __restrict__ W,
    const float* __restrict__ bias,
    float* __restrict__ Cf, unsigned short* __restrict__ Cb,
    int M, int N, int K, int relu)
{
  __shared__ __align__(16) short As[128 * 32];
  __shared__ __align__(16) short Ws[128 * 32];
  int tid = threadIdx.x;
  int lane = tid & 63, w = tid >> 6;
  int wr = w >> 1, wc = w & 1;
  int bm = blockIdx.y * 128, bn = blockIdx.x * 128;

  f32x4 acc[4][4];
  #pragma unroll
  for (int m = 0; m < 4; ++m)
    #pragma unroll
    for (int n = 0; n < 4; ++n) acc[m][n] = (f32x4){0.f, 0.f, 0.f, 0.f};

  int srow = tid >> 2;
  int skB  = (tid & 3) * 16;
  const char* pa0 = (const char*)(A + (size_t)(bm + srow) * K) + skB;
  const char* pa1 = (const char*)(A + (size_t)(bm + 64 + srow) * K) + skB;
  const char* pw0 = (const char*)(W + (size_t)(bn + srow) * K) + skB;
  const char* pw1 = (const char*)(W + (size_t)(bn + 64 + srow) * K) + skB;
  char* lA0 = (char*)As + w * 1024;
  char* lA1 = (char*)As + 4096 + w * 1024;
  char* lW0 = (char*)Ws + w * 1024;
  char* lW1 = (char*)Ws + 4096 + w * 1024;

  int r = lane & 15, k8 = lane >> 4;
  const bf16x8* Arow = (const bf16x8*)As;
  const bf16x8* Wrow = (const bf16x8*)Ws;

  for (int k0 = 0; k0 < K; k0 += 32) {
    load_lds16(pa0, lA0);
    load_lds16(pa1, lA1);
    load_lds16(pw0, lW0);
    load_lds16(pw1, lW1);
    pa0 += 64; pa1 += 64; pw0 += 64; pw1 += 64;
    __syncthreads();
    bf16x8 aF[4], bF[4];
    #pragma unroll
    for (int m = 0; m < 4; ++m) aF[m] = Arow[(wr * 64 + m * 16 + r) * 4 + k8];
    #pragma unroll
    for (int n = 0; n < 4; ++n) bF[n] = Wrow[(wc * 64 + n * 16 + r) * 4 + k8];
    #pragma unroll
    for (int m = 0; m < 4; ++m)
      #pragma unroll
      for (int n = 0; n < 4; ++n)
        acc[m][n] = __builtin_amdgcn_mfma_f32_16x16x32_bf16(aF[m], bF[n], acc[m][n], 0, 0, 0);
    __syncthreads();
  }

  int orow0 = bm + wr * 64 + (lane >> 4) * 4;
  int ocol0 = bn + wc * 64 + (lane & 15);
  #pragma unroll
  for (int n = 0; n < 4; ++n) {
    int col = ocol0 + n * 16;
    float bv = bias[col];
    #pragma unroll
    for (int m = 0; m < 4; ++m) {
      int row = orow0 + m * 16;
      #pragma unroll
      for (int j = 0; j < 4; ++j) {
        float val = acc[m][n][j] + bv;
        if (relu) val = fmaxf(val, 0.f);
        size_t off = (size_t)(row + j) * N + col;
        if (Cf) Cf[off] = val; else Cb[off] = f2bf(val);
      }
    }
  }
}

// ---------- per-head transpose (bf16): v[b][j][h*64+d] -> vt[b][h][d][j] ----------
__global__ __launch_bounds__(256) void transpose_heads_bf16(
    const unsigned short* __restrict__ v, unsigned short* __restrict__ vt)
{
  __shared__ unsigned short t[64][65];
  int jt = blockIdx.x, h = blockIdx.y, b = blockIdx.z;
  int lane = threadIdx.x & 63, w = threadIdx.x >> 6;
  #pragma unroll
  for (int r = 0; r < 16; ++r) {
    int j = w + r * 4;
    t[j][lane] = v[((size_t)(b * S_ + jt * 64 + j)) * D_ + h * DK_ + lane];
  }
  __syncthreads();
  #pragma unroll
  for (int r = 0; r < 16; ++r) {
    int d = w + r * 4;
    vt[((size_t)((b * H_ + h) * DK_ + d)) * S_ + jt * 64 + lane] = t[lane][d];
  }
}

// ---------- R4/R7-verbatim QK tile: scores scaled + boundary-masked ----------
__device__ __forceinline__ f32x4 qk_tile(
    int kt, int qt, int i0, int g, int c15, int maskType,
    const unsigned short* kbase, bf16x8 aQ0, bf16x8 aQ1)
{
  const unsigned short* kr = kbase + (size_t)(kt * 16 + c15) * D_;
  bf16x8 bK0 = *(const bf16x8*)(kr);
  bf16x8 bK1 = *(const bf16x8*)(kr + 32);
  f32x4 c = (f32x4){0.f, 0.f, 0.f, 0.f};
  c = __builtin_amdgcn_mfma_f32_16x16x32_bf16(aQ0, bK0, c, 0, 0, 0);
  c = __builtin_amdgcn_mfma_f32_16x16x32_bf16(aQ1, bK1, c, 0, 0, 0);
  #pragma unroll
  for (int r = 0; r < 4; ++r) c[r] *= 0.125f;
  if (kt == qt) {
    int j = kt * 16 + c15;
    #pragma unroll
    for (int r = 0; r < 4; ++r) {
      int i = i0 + 4 * g + r;
      bool valid = maskType ? (j <= i) : (j < i);
      if (!valid) c[r] = -1e30f;
    }
  }
  return c;
}

// ---------- MFMA attention: lane-private score cache in GLOBAL scratch ----------
// All score-cache accesses are lane-private (each lane rereads exactly what it
// wrote), so the cache lives in global scratch with per-tile lane-major layout
// (tile block = 512B, lane l owns bytes [l*8, l*8+8)) -> perfectly coalesced.
// LDS holds only the P buffer -> occupancy is VGPR-capped (8 waves/SIMD).
#define PSTRIDE 40
__global__ __launch_bounds__(256) void attn_mfma3(
    const unsigned short* __restrict__ qkb,   // q==k bf16 [b][s][D]
    const unsigned short* __restrict__ vtb,   // V^T bf16 [b][h][64][S]
    const float* __restrict__ gammas,
    unsigned short* scrg,                     // per-pair 33*512B score scratch
    unsigned short* __restrict__ ao,
    int maskType)
{
  __shared__ __align__(16) unsigned short P_all[4][16][PSTRIDE];
  int tid = threadIdx.x;
  int lane = tid & 63, w = tid >> 6;
  int bid = blockIdx.x;
  int pp = bid & 7;
  int h = (bid >> 3) & (H_ - 1);
  int b = bid >> 6;
  int pairIdx = w >> 1, wp = w & 1;
  int p = pp * 2 + pairIdx;                     // 0..15
  int qt = wp ? (31 - p) : p;                   // complementary pair
  unsigned short (*P_lds)[PSTRIDE] = P_all[w];
  int i0 = qt * 16;
  int c15 = lane & 15, g = lane >> 4;

  // per-wave lane-private score scratch base (shorts)
  unsigned short* swave = scrg
      + (size_t)((b * H_ + h) * 16 + p) * (33 * 256)
      + (wp ? (size_t)(p + 1) * 256 : 0)
      + lane * 4;

  const unsigned short* qbase =
      qkb + ((size_t)(b * S_ + i0 + c15)) * D_ + h * DK_ + g * 8;
  bf16x8 aQ0 = *(const bf16x8*)(qbase);
  bf16x8 aQ1 = *(const bf16x8*)(qbase + 32);
  const unsigned short* kbase = qkb + ((size_t)b * S_) * D_ + h * DK_ + g * 8;

  float gam = gammas[h];
  float gneg = -((gam > 20.f) ? gam : log1pf(__expf(gam)));   // -softplus < 0

  // ---- phase 1: QK once; f16 scores -> global scratch; running m1 ----
  float m1[4] = {-1e30f, -1e30f, -1e30f, -1e30f};
  for (int kt = 0; kt <= qt; ++kt) {
    f32x4 c = qk_tile(kt, qt, i0, g, c15, maskType, kbase, aQ0, aQ1);
    int lo = (int)f2h(c[0]) | ((int)f2h(c[1]) << 16);
    int hi = (int)f2h(c[2]) | ((int)f2h(c[3]) << 16);
    *(int2*)(swave + (size_t)kt * 256) = make_int2(lo, hi);
    #pragma unroll
    for (int r = 0; r < 4; ++r) m1[r] = fmaxf(m1[r], c[r]);
  }
  #pragma unroll
  for (int r = 0; r < 4; ++r)
    #pragma unroll
    for (int off = 1; off < 16; off <<= 1)
      m1[r] = fmaxf(m1[r], __shfl_xor(m1[r], off, 64));
  asm volatile("s_waitcnt vmcnt(0)" ::: "memory");   // stores landed before reread
  __builtin_amdgcn_sched_barrier(0);

  // ---- phase 2: sum1 from scratch scores (fixed m1) ----
  float sum1[4] = {0.f, 0.f, 0.f, 0.f};
  for (int kt = 0; kt <= qt; ++kt) {
    int2 d = *(const int2*)(swave + (size_t)kt * 256);
    float s0 = h2f((unsigned short)(d.x & 0xffff));
    float s1 = h2f((unsigned short)((unsigned)d.x >> 16));
    float s2_ = h2f((unsigned short)(d.y & 0xffff));
    float s3 = h2f((unsigned short)((unsigned)d.y >> 16));
    sum1[0] += __expf(s0 - m1[0]);
    sum1[1] += __expf(s1 - m1[1]);
    sum1[2] += __expf(s2_ - m1[2]);
    sum1[3] += __expf(s3 - m1[3]);
  }
  #pragma unroll
  for (int r = 0; r < 4; ++r)
    #pragma unroll
    for (int off = 1; off < 16; off <<= 1)
      sum1[r] += __shfl_xor(sum1[r], off, 64);
  float inv1[4], m2b[4];
  #pragma unroll
  for (int r = 0; r < 4; ++r) {
    inv1[r] = (sum1[r] > 0.f) ? 1.f / sum1[r] : 0.f;
    m2b[r] = fmaxf(m1[r], 0.f);
  }

  // ---- phase 3: DPP cumsum + decay + rescore + P + fused PV ----
  f32x4 acc[4];
  #pragma unroll
  for (int dt = 0; dt < 4; ++dt) acc[dt] = (f32x4){0.f, 0.f, 0.f, 0.f};
  float sum2[4] = {0.f, 0.f, 0.f, 0.f};
  {
    float carry[4] = {0.f, 0.f, 0.f, 0.f};
    const unsigned short* vbase =
        vtb + (((size_t)(b * H_ + h) * DK_) + c15) * S_ + g * 8;

    #pragma unroll
    for (int jc = 0; jc < 16; ++jc) {
      if (jc * 2 <= qt) {
        #pragma unroll
        for (int t2 = 0; t2 < 2; ++t2) {
          int kt = jc * 2 + t2;
          if (kt <= qt) {
            int2 d = *(const int2*)(swave + (size_t)kt * 256);
            float sv[4];
            sv[0] = h2f((unsigned short)(d.x & 0xffff));
            sv[1] = h2f((unsigned short)((unsigned)d.x >> 16));
            sv[2] = h2f((unsigned short)(d.y & 0xffff));
            sv[3] = h2f((unsigned short)((unsigned)d.y >> 16));
            #pragma unroll
            for (int r = 0; r < 4; ++r) {
              float e = __expf(sv[r] - m1[r]);
              float p2 = scan16_dpp(e);           // inclusive scan over c15
              float tot = bcast15(p2);            // row total (lane|15)
              float cum = carry[r] + p2;
              carry[r] += tot;
              float suffix = sum1[r] - cum;
              int i = i0 + 4 * g + r;
              float pos = fabsf((float)(kt * 16 + c15 - i));
              float dist = sqrtf(fmaxf(suffix * inv1[r] * pos, 0.f));
              float te = fminf(fmaxf(__expf(dist * gneg), 1e-5f), 1e5f);
              float s2 = sv[r] * te;
              float e2 = __expf(s2 - m2b[r]);
              sum2[r] += e2;
              P_lds[4 * g + r][t2 * 16 + c15] = f2bf(e2);
            }
          } else {
            #pragma unroll
            for (int r = 0; r < 4; ++r) P_lds[4 * g + r][t2 * 16 + c15] = 0;
          }
        }
        asm volatile("s_waitcnt lgkmcnt(0)" ::: "memory");
        __builtin_amdgcn_sched_barrier(0);
        bf16x8 aP = *(const bf16x8*)&P_lds[c15][g * 8];
        const unsigned short* vr = vbase + (size_t)jc * 32;
        #pragma unroll
        for (int dt = 0; dt < 4; ++dt) {
          bf16x8 bV = *(const bf16x8*)(vr + (size_t)dt * 16 * S_);
          acc[dt] = __builtin_amdgcn_mfma_f32_16x16x32_bf16(aP, bV, acc[dt], 0, 0, 0);
        }
        // post-MFMA fence not needed: aP ds_read->MFMA dep is compiler-tracked;
        // may-alias store/load ordering keeps next-iter P writes after this read.
      }
    }
  }
  #pragma unroll
  for (int r = 0; r < 4; ++r)
    #pragma unroll
    for (int off = 1; off < 16; off <<= 1)
      sum2[r] += __shfl_xor(sum2[r], off, 64);

  // ---- epilogue: normalize (guarded), zeroPad row0, store bf16 ----
  int zp = (maskType == 0 && qt == 0);
  #pragma unroll
  for (int dt = 0; dt < 4; ++dt) {
    #pragma unroll
    for (int r = 0; r < 4; ++r) {
      int i = i0 + 4 * g + r;
      float ns = (sum2[r] > 0.f) ? 1.f / sum2[r] : 0.f;
      float val = acc[dt][r] * ns;
      if (zp && (4 * g + r) == 0) val = 0.f;
      ao[((size_t)(b * S_ + i)) * D_ + h * DK_ + dt * 16 + c15] = f2bf(val);
    }
  }
}

// ---------- wave/block reduce + residual LN (also emits bf16 x) ----------
__device__ __forceinline__ float blockReduceSum256(float v, float* red) {
  #pragma unroll
  for (int off = 32; off > 0; off >>= 1) v += __shfl_down(v, off, 64);
  int lane = threadIdx.x & 63, wid = threadIdx.x >> 6;
  __syncthreads();
  if (lane == 0) red[wid] = v;
  __syncthreads();
  return red[0] + red[1] + red[2] + red[3];
}

__global__ __launch_bounds__(256) void add_ln(
    float* __restrict__ x, unsigned short* __restrict__ xb,
    const float* __restrict__ r,
    const float* __restrict__ g, const float* __restrict__ b)
{
  int row = blockIdx.x;
  int t = threadIdx.x;
  float* xr = x + (size_t)row * D_;
  unsigned short* xbr = xb + (size_t)row * D_;
  const float* rr = r + (size_t)row * D_;
  float v0 = xr[t] + rr[t];
  float v1 = xr[t + 256] + rr[t + 256];
  __shared__ float red[4];
  float s = blockReduceSum256(v0 + v1, red);
  float mu = s * (1.0f / 512.0f);
  float d0 = v0 - mu, d1 = v1 - mu;
  float sq = blockReduceSum256(d0 * d0 + d1 * d1, red);
  float rstd = rsqrtf(sq * (1.0f / 512.0f) + 1e-5f);
  float o0 = d0 * rstd * g[t] + b[t];
  float o1 = d1 * rstd * g[t + 256] + b[t + 256];
  xr[t] = o0;
  xr[t + 256] = o1;
  xbr[t] = f2bf(o0);
  xbr[t + 256] = f2bf(o1);
}

static inline void cvt(const float* in, unsigned short* out, size_t n, hipStream_t s) {
  size_t n8 = n / 8;
  int blocks = (int)((n8 + 255) / 256);
  if (blocks > 2048) blocks = 2048;
  cvt_f32_bf16<<<blocks, 256, 0, s>>>(in, out, n8);
}

extern "C" void kernel_launch(void* const* d_in, const int* in_sizes, int n_in,
                              void* d_out, int out_size, void* d_ws, size_t ws_size,
                              hipStream_t stream) {
  const float* q_embed  = (const float*)d_in[0];
  const float* qa_embed = (const float*)d_in[1];
  const float* Wk = (const float*)d_in[2];
  const float* bk = (const float*)d_in[3];
  const float* Wv = (const float*)d_in[4];
  const float* bv = (const float*)d_in[5];
  const float* Wo = (const float*)d_in[6];
  const float* bo = (const float*)d_in[7];
  const float* gammas = (const float*)d_in[8];
  const float* ln1_g = (const float*)d_in[9];
  const float* ln1_b = (const float*)d_in[10];
  const float* W1 = (const float*)d_in[11];
  const float* b1 = (const float*)d_in[12];
  const float* W2 = (const float*)d_in[13];
  const float* b2 = (const float*)d_in[14];
  const float* ln2_g = (const float*)d_in[15];
  const float* ln2_b = (const float*)d_in[16];

  float* x = (float*)d_out;
  const size_t NTOK = (size_t)B_ * S_;      // 16384
  const size_t ND = NTOK * D_;

  float* qkf = (float*)d_ws;                               // f32 scratch [ND]
  unsigned short* xb    = (unsigned short*)(qkf + ND);     // bf16 [ND]
  unsigned short* valsb = xb + ND;
  unsigned short* qkb   = valsb + ND;
  unsigned short* vb    = qkb + ND;
  unsigned short* vtb   = vb + ND;
  unsigned short* aob   = vtb + ND;
  unsigned short* wkb   = aob + ND;
  unsigned short* wvb   = wkb + (size_t)L_ * D_ * D_;
  unsigned short* wob   = wvb + (size_t)L_ * D_ * D_;
  unsigned short* w1b   = wob + (size_t)L_ * D_ * D_;
  unsigned short* w2b   = w1b + (size_t)L_ * DFF_ * D_;
  unsigned short* scrg  = w2b + (size_t)L_ * D_ * DFF_;    // 4096 pairs x 33*256 shorts (69MB)
  unsigned short* ffnb  = qkb;   // [NTOK*DFF] aliases qkb+vb+vtb+aob (dead in FFN phase)

  // x (f32) + xb (bf16) from q_embed in one pass
  {
    size_t n8 = ND / 8;
    copy_cvt<<<2048, 256, 0, stream>>>(q_embed, x, xb, n8);
  }

  cvt(Wk, wkb, (size_t)L_ * D_ * D_, stream);
  cvt(Wv, wvb, (size_t)L_ * D_ * D_, stream);
  cvt(Wo, wob, (size_t)L_ * D_ * D_, stream);
  cvt(W1, w1b, (size_t)L_ * DFF_ * D_, stream);
  cvt(W2, w2b, (size_t)L_ * DFF_ * D_, stream);
  cvt(qa_embed, valsb, ND, stream);

  dim3 gproj(D_ / 128, NTOK / 128);
  dim3 gf1(DFF_ / 128, NTOK / 128);
  dim3 gf2(D_ / 128, NTOK / 128);
  dim3 gtr(S_ / 64, H_, B_);
  int gattn = B_ * H_ * 8;   // 2048 blocks, 2 complementary pairs (4 waves) each

  for (int l = 0; l < L_; ++l) {
    int first = (l % 2 == 0);
    const unsigned short* vA = first ? valsb : xb;

    gemm_bt_bf16<<<gproj, 256, 0, stream>>>(xb, wkb + (size_t)l * D_ * D_, bk + l * D_,
                                            nullptr, qkb, (int)NTOK, D_, D_, 0);
    gemm_bt_bf16<<<gproj, 256, 0, stream>>>(vA, wvb + (size_t)l * D_ * D_, bv + l * D_,
                                            nullptr, vb, (int)NTOK, D_, D_, 0);
    transpose_heads_bf16<<<gtr, 256, 0, stream>>>(vb, vtb);
    attn_mfma3<<<gattn, 256, 0, stream>>>(qkb, vtb, gammas + l * H_, scrg, aob,
                                          first ? 0 : 1);
    gemm_bt_bf16<<<gproj, 256, 0, stream>>>(aob, wob + (size_t)l * D_ * D_, bo + l * D_,
                                            qkf, nullptr, (int)NTOK, D_, D_, 0);
    add_ln<<<(int)NTOK, 256, 0, stream>>>(x, xb, qkf, ln1_g + l * D_, ln1_b + l * D_);
    if (first) {
      gemm_bt_bf16<<<gf1, 256, 0, stream>>>(xb, w1b + (size_t)l * DFF_ * D_, b1 + l * DFF_,
                                            nullptr, ffnb, (int)NTOK, DFF_, D_, 1);
      gemm_bt_bf16<<<gf2, 256, 0, stream>>>(ffnb, w2b + (size_t)l * D_ * DFF_, b2 + l * D_,
                                            qkf, nullptr, (int)NTOK, D_, DFF_, 0);
      add_ln<<<(int)NTOK, 256, 0, stream>>>(x, xb, qkf, ln2_g + l * D_, ln2_b + l * D_);
    }
  }
}

// Round 15
// 1133.257 us; speedup vs baseline: 1.0948x; 1.0948x over previous
//
#include <hip/hip_runtime.h>
#include <hip/hip_bf16.h>
#include <math.h>

#define B_ 32
#define S_ 512
#define D_ 512
#define H_ 8
#define DK_ 64
#define DFF_ 2048
#define L_ 4

typedef __attribute__((ext_vector_type(8))) short bf16x8;
typedef __attribute__((ext_vector_type(4))) float f32x4;

__device__ __forceinline__ unsigned short f2bf(float x) {
  union { float f; unsigned u; } v; v.f = x;
  unsigned r = v.u + 0x7fff + ((v.u >> 16) & 1);   // round-nearest-even
  return (unsigned short)(r >> 16);
}

__device__ __forceinline__ unsigned short f2h(float x) {
  union { _Float16 h; unsigned short u; } v;
  v.h = (_Float16)x;
  return v.u;
}
__device__ __forceinline__ float h2f(unsigned short u) {
  union { _Float16 h; unsigned short u; } v;
  v.u = u;
  return (float)v.h;
}

// inclusive 16-lane prefix sum via DPP row_shr (VALU only). bound_ctrl -> 0-fill.
#define DPP_ADD_SHR(x, N)                                                       \
  {                                                                             \
    int _t = __builtin_amdgcn_update_dpp(0, __float_as_int(x), 0x110 + (N),     \
                                         0xf, 0xf, true);                       \
    (x) += __int_as_float(_t);                                                  \
  }
__device__ __forceinline__ float scan16_dpp(float x) {
  DPP_ADD_SHR(x, 1);
  DPP_ADD_SHR(x, 2);
  DPP_ADD_SHR(x, 4);
  DPP_ADD_SHR(x, 8);
  return x;
}
// broadcast lane (id|15)'s value to all lanes of each 16-lane row
__device__ __forceinline__ float bcast15(float x) {
  return __int_as_float(__builtin_amdgcn_ds_swizzle(__float_as_int(x), 0x1FF));
}

__device__ __forceinline__ void load_lds16(const void* g, void* l) {
  __builtin_amdgcn_global_load_lds(
      (const __attribute__((address_space(1))) void*)g,
      (__attribute__((address_space(3))) void*)l, 16, 0, 0);
}

// ---------- f32 -> bf16 convert ----------
__global__ __launch_bounds__(256) void cvt_f32_bf16(
    const float* __restrict__ in, unsigned short* __restrict__ out, size_t n8)
{
  size_t idx = (size_t)blockIdx.x * 256 + threadIdx.x;
  size_t stride = (size_t)gridDim.x * 256;
  for (size_t i = idx; i < n8; i += stride) {
    const float4* p = (const float4*)(in + i * 8);
    float4 a = p[0], b = p[1];
    union { unsigned short u[8]; int4 v; } o;
    o.u[0] = f2bf(a.x); o.u[1] = f2bf(a.y); o.u[2] = f2bf(a.z); o.u[3] = f2bf(a.w);
    o.u[4] = f2bf(b.x); o.u[5] = f2bf(b.y); o.u[6] = f2bf(b.z); o.u[7] = f2bf(b.w);
    *(int4*)(out + i * 8) = o.v;
  }
}

// ---------- copy f32 + emit bf16 ----------
__global__ __launch_bounds__(256) void copy_cvt(
    const float* __restrict__ in, float* __restrict__ outf,
    unsigned short* __restrict__ outb, size_t n8)
{
  size_t idx = (size_t)blockIdx.x * 256 + threadIdx.x;
  size_t stride = (size_t)gridDim.x * 256;
  for (size_t i = idx; i < n8; i += stride) {
    const float4* p = (const float4*)(in + i * 8);
    float4 a = p[0], b = p[1];
    ((float4*)(outf + i * 8))[0] = a;
    ((float4*)(outf + i * 8))[1] = b;
    union { unsigned short u[8]; int4 v; } o;
    o.u[0] = f2bf(a.x); o.u[1] = f2bf(a.y); o.u[2] = f2bf(a.z); o.u[3] = f2bf(a.w);
    o.u[4] = f2bf(b.x); o.u[5] = f2bf(b.y); o.u[6] = f2bf(b.z); o.u[7] = f2bf(b.w);
    *(int4*)(outb + i * 8) = o.v;
  }
}

// ---------- bf16 MFMA GEMM: C[M,N] = A[M,K] @ W[N,K]^T + bias ----------
__global__ __launch_bounds__(256) void gemm_bt_bf16(
    const unsigned short* __restrict__ A, const unsigned short* __restrict__ W,
    const float* __restrict__ bias,
    float* __restrict__ Cf, unsigned short* __restrict__ Cb,
    int M, int N, int K, int relu)
{
  __shared__ __align__(16) short As[128 * 32];
  __shared__ __align__(16) short Ws[128 * 32];
  int tid = threadIdx.x;
  int lane = tid & 63, w = tid >> 6;
  int wr = w >> 1, wc = w & 1;
  int bm = blockIdx.y * 128, bn = blockIdx.x * 128;

  f32x4 acc[4][4];
  #pragma unroll
  for (int m = 0; m < 4; ++m)
    #pragma unroll
    for (int n = 0; n < 4; ++n) acc[m][n] = (f32x4){0.f, 0.f, 0.f, 0.f};

  int srow = tid >> 2;
  int skB  = (tid & 3) * 16;
  const char* pa0 = (const char*)(A + (size_t)(bm + srow) * K) + skB;
  const char* pa1 = (const char*)(A + (size_t)(bm + 64 + srow) * K) + skB;
  const char* pw0 = (const char*)(W + (size_t)(bn + srow) * K) + skB;
  const char* pw1 = (const char*)(W + (size_t)(bn + 64 + srow) * K) + skB;
  char* lA0 = (char*)As + w * 1024;
  char* lA1 = (char*)As + 4096 + w * 1024;
  char* lW0 = (char*)Ws + w * 1024;
  char* lW1 = (char*)Ws + 4096 + w * 1024;

  int r = lane & 15, k8 = lane >> 4;
  const bf16x8* Arow = (const bf16x8*)As;
  const bf16x8* Wrow = (const bf16x8*)Ws;

  for (int k0 = 0; k0 < K; k0 += 32) {
    load_lds16(pa0, lA0);
    load_lds16(pa1, lA1);
    load_lds16(pw0, lW0);
    load_lds16(pw1, lW1);
    pa0 += 64; pa1 += 64; pw0 += 64; pw1 += 64;
    __syncthreads();
    bf16x8 aF[4], bF[4];
    #pragma unroll
    for (int m = 0; m < 4; ++m) aF[m] = Arow[(wr * 64 + m * 16 + r) * 4 + k8];
    #pragma unroll
    for (int n = 0; n < 4; ++n) bF[n] = Wrow[(wc * 64 + n * 16 + r) * 4 + k8];
    #pragma unroll
    for (int m = 0; m < 4; ++m)
      #pragma unroll
      for (int n = 0; n < 4; ++n)
        acc[m][n] = __builtin_amdgcn_mfma_f32_16x16x32_bf16(aF[m], bF[n], acc[m][n], 0, 0, 0);
    __syncthreads();
  }

  int orow0 = bm + wr * 64 + (lane >> 4) * 4;
  int ocol0 = bn + wc * 64 + (lane & 15);
  #pragma unroll
  for (int n = 0; n < 4; ++n) {
    int col = ocol0 + n * 16;
    float bv = bias[col];
    #pragma unroll
    for (int m = 0; m < 4; ++m) {
      int row = orow0 + m * 16;
      #pragma unroll
      for (int j = 0; j < 4; ++j) {
        float val = acc[m][n][j] + bv;
        if (relu) val = fmaxf(val, 0.f);
        size_t off = (size_t)(row + j) * N + col;
        if (Cf) Cf[off] = val; else Cb[off] = f2bf(val);
      }
    }
  }
}

// ---------- per-head transpose (bf16): v[b][j][h*64+d] -> vt[b][h][d][j] ----------
__global__ __launch_bounds__(256) void transpose_heads_bf16(
    const unsigned short* __restrict__ v, unsigned short* __restrict__ vt)
{
  __shared__ unsigned short t[64][65];
  int jt = blockIdx.x, h = blockIdx.y, b = blockIdx.z;
  int lane = threadIdx.x & 63, w = threadIdx.x >> 6;
  #pragma unroll
  for (int r = 0; r < 16; ++r) {
    int j = w + r * 4;
    t[j][lane] = v[((size_t)(b * S_ + jt * 64 + j)) * D_ + h * DK_ + lane];
  }
  __syncthreads();
  #pragma unroll
  for (int r = 0; r < 16; ++r) {
    int d = w + r * 4;
    vt[((size_t)((b * H_ + h) * DK_ + d)) * S_ + jt * 64 + lane] = t[lane][d];
  }
}

// ---------- R4/R7-verbatim QK tile: scores scaled + boundary-masked ----------
__device__ __forceinline__ f32x4 qk_tile(
    int kt, int qt, int i0, int g, int c15, int maskType,
    const unsigned short* kbase, bf16x8 aQ0, bf16x8 aQ1)
{
  const unsigned short* kr = kbase + (size_t)(kt * 16 + c15) * D_;
  bf16x8 bK0 = *(const bf16x8*)(kr);
  bf16x8 bK1 = *(const bf16x8*)(kr + 32);
  f32x4 c = (f32x4){0.f, 0.f, 0.f, 0.f};
  c = __builtin_amdgcn_mfma_f32_16x16x32_bf16(aQ0, bK0, c, 0, 0, 0);
  c = __builtin_amdgcn_mfma_f32_16x16x32_bf16(aQ1, bK1, c, 0, 0, 0);
  #pragma unroll
  for (int r = 0; r < 4; ++r) c[r] *= 0.125f;
  if (kt == qt) {
    int j = kt * 16 + c15;
    #pragma unroll
    for (int r = 0; r < 4; ++r) {
      int i = i0 + 4 * g + r;
      bool valid = maskType ? (j <= i) : (j < i);
      if (!valid) c[r] = -1e30f;
    }
  }
  return c;
}

// ---------- MFMA attention: complementary pairs, DPP scan, swizzled LDS caches ----------
// All LDS ops are plain C++ loads/stores: the compiler orders may-aliasing LDS
// accesses and inserts precise lgkmcnt for data arrival; within a wave DS ops
// execute in issue order, so cross-lane P exchange needs no explicit fence.
#define PSTRIDE 40
__global__ __launch_bounds__(256) void attn_mfma3(
    const unsigned short* __restrict__ qkb,   // q==k bf16 [b][s][D]
    const unsigned short* __restrict__ vtb,   // V^T bf16 [b][h][64][S]
    const float* __restrict__ gammas,
    unsigned short* __restrict__ ao,
    int maskType)
{
  __shared__ __align__(16) unsigned short scr_all[2][33 * 16][16];  // per-pair score cache
  __shared__ __align__(16) unsigned short P_all[4][16][PSTRIDE];
  int tid = threadIdx.x;
  int lane = tid & 63, w = tid >> 6;
  int bid = blockIdx.x;
  int pp = bid & 7;
  int h = (bid >> 3) & (H_ - 1);
  int b = bid >> 6;
  int pairIdx = w >> 1, wp = w & 1;
  int p = pp * 2 + pairIdx;                     // 0..15
  int qt = wp ? (31 - p) : p;                   // complementary pair
  int rowbase = wp ? (p + 1) * 16 : 0;
  unsigned short (*scr)[16] = &scr_all[pairIdx][rowbase];
  unsigned short (*P_lds)[PSTRIDE] = P_all[w];
  int i0 = qt * 16;
  int c15 = lane & 15, g = lane >> 4;
  int scol = 4 * ((g + (c15 >> 2)) & 3);        // bank-swizzled scr column

  const unsigned short* qbase =
      qkb + ((size_t)(b * S_ + i0 + c15)) * D_ + h * DK_ + g * 8;
  bf16x8 aQ0 = *(const bf16x8*)(qbase);
  bf16x8 aQ1 = *(const bf16x8*)(qbase + 32);
  const unsigned short* kbase = qkb + ((size_t)b * S_) * D_ + h * DK_ + g * 8;

  float gam = gammas[h];
  float gneg = -((gam > 20.f) ? gam : log1pf(__expf(gam)));   // -softplus < 0

  // ---- phase 1: QK once; f16 scores -> LDS (swizzled); running m1 ----
  float m1[4] = {-1e30f, -1e30f, -1e30f, -1e30f};
  for (int kt = 0; kt <= qt; ++kt) {
    f32x4 c = qk_tile(kt, qt, i0, g, c15, maskType, kbase, aQ0, aQ1);
    int j = kt * 16 + c15;
    int lo = (int)f2h(c[0]) | ((int)f2h(c[1]) << 16);
    int hi = (int)f2h(c[2]) | ((int)f2h(c[3]) << 16);
    *(int2*)&scr[j][scol] = make_int2(lo, hi);
    #pragma unroll
    for (int r = 0; r < 4; ++r) m1[r] = fmaxf(m1[r], c[r]);
  }
  #pragma unroll
  for (int r = 0; r < 4; ++r)
    #pragma unroll
    for (int off = 1; off < 16; off <<= 1)
      m1[r] = fmaxf(m1[r], __shfl_xor(m1[r], off, 64));
  // no fence: phase-2 reads are same-lane addresses; DS per-wave is in-order
  // and the compiler orders may-aliasing LDS accesses + inserts lgkmcnt.

  // ---- phase 2: sum1 from LDS scores (fixed m1) ----
  float sum1[4] = {0.f, 0.f, 0.f, 0.f};
  for (int kt = 0; kt <= qt; ++kt) {
    int j = kt * 16 + c15;
    int2 d = *(const int2*)&scr[j][scol];
    float s0 = h2f((unsigned short)(d.x & 0xffff));
    float s1 = h2f((unsigned short)((unsigned)d.x >> 16));
    float s2_ = h2f((unsigned short)(d.y & 0xffff));
    float s3 = h2f((unsigned short)((unsigned)d.y >> 16));
    sum1[0] += __expf(s0 - m1[0]);
    sum1[1] += __expf(s1 - m1[1]);
    sum1[2] += __expf(s2_ - m1[2]);
    sum1[3] += __expf(s3 - m1[3]);
  }
  #pragma unroll
  for (int r = 0; r < 4; ++r)
    #pragma unroll
    for (int off = 1; off < 16; off <<= 1)
      sum1[r] += __shfl_xor(sum1[r], off, 64);
  float inv1[4], m2b[4];
  #pragma unroll
  for (int r = 0; r < 4; ++r) {
    inv1[r] = (sum1[r] > 0.f) ? 1.f / sum1[r] : 0.f;
    m2b[r] = fmaxf(m1[r], 0.f);
  }

  // ---- phase 3: DPP cumsum + decay + rescore + P + fused PV ----
  f32x4 acc[4];
  #pragma unroll
  for (int dt = 0; dt < 4; ++dt) acc[dt] = (f32x4){0.f, 0.f, 0.f, 0.f};
  float sum2[4] = {0.f, 0.f, 0.f, 0.f};
  {
    float carry[4] = {0.f, 0.f, 0.f, 0.f};
    const unsigned short* vbase =
        vtb + (((size_t)(b * H_ + h) * DK_) + c15) * S_ + g * 8;

    #pragma unroll
    for (int jc = 0; jc < 16; ++jc) {
      if (jc * 2 <= qt) {
        #pragma unroll
        for (int t2 = 0; t2 < 2; ++t2) {
          int kt = jc * 2 + t2;
          if (kt <= qt) {
            int j = kt * 16 + c15;
            int2 d = *(const int2*)&scr[j][scol];
            float sv[4];
            sv[0] = h2f((unsigned short)(d.x & 0xffff));
            sv[1] = h2f((unsigned short)((unsigned)d.x >> 16));
            sv[2] = h2f((unsigned short)(d.y & 0xffff));
            sv[3] = h2f((unsigned short)((unsigned)d.y >> 16));
            #pragma unroll
            for (int r = 0; r < 4; ++r) {
              float e = __expf(sv[r] - m1[r]);
              float p2 = scan16_dpp(e);           // inclusive scan over c15
              float tot = bcast15(p2);            // row total (lane|15)
              float cum = carry[r] + p2;
              carry[r] += tot;
              float suffix = sum1[r] - cum;
              int i = i0 + 4 * g + r;
              float pos = fabsf((float)(kt * 16 + c15 - i));
              float dist = sqrtf(fmaxf(suffix * inv1[r] * pos, 0.f));
              float te = fminf(fmaxf(__expf(dist * gneg), 1e-5f), 1e5f);
              float s2 = sv[r] * te;
              float e2 = __expf(s2 - m2b[r]);
              sum2[r] += e2;
              P_lds[4 * g + r][t2 * 16 + c15] = f2bf(e2);
            }
          } else {
            #pragma unroll
            for (int r = 0; r < 4; ++r) P_lds[4 * g + r][t2 * 16 + c15] = 0;
          }
        }
        // no explicit fence: all lanes issue P writes before the P read
        // (single instruction stream), DS per-wave is in-order, and the
        // compiler's alias analysis orders the LDS ops + inserts lgkmcnt.
        bf16x8 aP = *(const bf16x8*)&P_lds[c15][g * 8];
        const unsigned short* vr = vbase + (size_t)jc * 32;
        #pragma unroll
        for (int dt = 0; dt < 4; ++dt) {
          bf16x8 bV = *(const bf16x8*)(vr + (size_t)dt * 16 * S_);
          acc[dt] = __builtin_amdgcn_mfma_f32_16x16x32_bf16(aP, bV, acc[dt], 0, 0, 0);
        }
      }
    }
  }
  #pragma unroll
  for (int r = 0; r < 4; ++r)
    #pragma unroll
    for (int off = 1; off < 16; off <<= 1)
      sum2[r] += __shfl_xor(sum2[r], off, 64);

  // ---- epilogue: normalize (guarded), zeroPad row0, store bf16 ----
  int zp = (maskType == 0 && qt == 0);
  #pragma unroll
  for (int dt = 0; dt < 4; ++dt) {
    #pragma unroll
    for (int r = 0; r < 4; ++r) {
      int i = i0 + 4 * g + r;
      float ns = (sum2[r] > 0.f) ? 1.f / sum2[r] : 0.f;
      float val = acc[dt][r] * ns;
      if (zp && (4 * g + r) == 0) val = 0.f;
      ao[((size_t)(b * S_ + i)) * D_ + h * DK_ + dt * 16 + c15] = f2bf(val);
    }
  }
}

// ---------- wave/block reduce + residual LN (also emits bf16 x) ----------
__device__ __forceinline__ float blockReduceSum256(float v, float* red) {
  #pragma unroll
  for (int off = 32; off > 0; off >>= 1) v += __shfl_down(v, off, 64);
  int lane = threadIdx.x & 63, wid = threadIdx.x >> 6;
  __syncthreads();
  if (lane == 0) red[wid] = v;
  __syncthreads();
  return red[0] + red[1] + red[2] + red[3];
}

__global__ __launch_bounds__(256) void add_ln(
    float* __restrict__ x, unsigned short* __restrict__ xb,
    const float* __restrict__ r,
    const float* __restrict__ g, const float* __restrict__ b)
{
  int row = blockIdx.x;
  int t = threadIdx.x;
  float* xr = x + (size_t)row * D_;
  unsigned short* xbr = xb + (size_t)row * D_;
  const float* rr = r + (size_t)row * D_;
  float v0 = xr[t] + rr[t];
  float v1 = xr[t + 256] + rr[t + 256];
  __shared__ float red[4];
  float s = blockReduceSum256(v0 + v1, red);
  float mu = s * (1.0f / 512.0f);
  float d0 = v0 - mu, d1 = v1 - mu;
  float sq = blockReduceSum256(d0 * d0 + d1 * d1, red);
  float rstd = rsqrtf(sq * (1.0f / 512.0f) + 1e-5f);
  float o0 = d0 * rstd * g[t] + b[t];
  float o1 = d1 * rstd * g[t + 256] + b[t + 256];
  xr[t] = o0;
  xr[t + 256] = o1;
  xbr[t] = f2bf(o0);
  xbr[t + 256] = f2bf(o1);
}

static inline void cvt(const float* in, unsigned short* out, size_t n, hipStream_t s) {
  size_t n8 = n / 8;
  int blocks = (int)((n8 + 255) / 256);
  if (blocks > 2048) blocks = 2048;
  cvt_f32_bf16<<<blocks, 256, 0, s>>>(in, out, n8);
}

extern "C" void kernel_launch(void* const* d_in, const int* in_sizes, int n_in,
                              void* d_out, int out_size, void* d_ws, size_t ws_size,
                              hipStream_t stream) {
  const float* q_embed  = (const float*)d_in[0];
  const float* qa_embed = (const float*)d_in[1];
  const float* Wk = (const float*)d_in[2];
  const float* bk = (const float*)d_in[3];
  const float* Wv = (const float*)d_in[4];
  const float* bv = (const float*)d_in[5];
  const float* Wo = (const float*)d_in[6];
  const float* bo = (const float*)d_in[7];
  const float* gammas = (const float*)d_in[8];
  const float* ln1_g = (const float*)d_in[9];
  const float* ln1_b = (const float*)d_in[10];
  const float* W1 = (const float*)d_in[11];
  const float* b1 = (const float*)d_in[12];
  const float* W2 = (const float*)d_in[13];
  const float* b2 = (const float*)d_in[14];
  const float* ln2_g = (const float*)d_in[15];
  const float* ln2_b = (const float*)d_in[16];

  float* x = (float*)d_out;
  const size_t NTOK = (size_t)B_ * S_;      // 16384
  const size_t ND = NTOK * D_;

  float* qkf = (float*)d_ws;                               // f32 scratch [ND]
  unsigned short* xb    = (unsigned short*)(qkf + ND);     // bf16 [ND]
  unsigned short* valsb = xb + ND;
  unsigned short* qkb   = valsb + ND;
  unsigned short* vb    = qkb + ND;
  unsigned short* vtb   = vb + ND;
  unsigned short* aob   = vtb + ND;
  unsigned short* wkb   = aob + ND;
  unsigned short* wvb   = wkb + (size_t)L_ * D_ * D_;
  unsigned short* wob   = wvb + (size_t)L_ * D_ * D_;
  unsigned short* w1b   = wob + (size_t)L_ * D_ * D_;
  unsigned short* w2b   = w1b + (size_t)L_ * DFF_ * D_;
  unsigned short* ffnb  = qkb;   // [NTOK*DFF] aliases qkb+vb+vtb+aob (dead in FFN phase)

  // x (f32) + xb (bf16) from q_embed in one pass
  {
    size_t n8 = ND / 8;
    copy_cvt<<<2048, 256, 0, stream>>>(q_embed, x, xb, n8);
  }

  cvt(Wk, wkb, (size_t)L_ * D_ * D_, stream);
  cvt(Wv, wvb, (size_t)L_ * D_ * D_, stream);
  cvt(Wo, wob, (size_t)L_ * D_ * D_, stream);
  cvt(W1, w1b, (size_t)L_ * DFF_ * D_, stream);
  cvt(W2, w2b, (size_t)L_ * DFF_ * D_, stream);
  cvt(qa_embed, valsb, ND, stream);

  dim3 gproj(D_ / 128, NTOK / 128);
  dim3 gf1(DFF_ / 128, NTOK / 128);
  dim3 gf2(D_ / 128, NTOK / 128);
  dim3 gtr(S_ / 64, H_, B_);
  int gattn = B_ * H_ * 8;   // 2048 blocks, 2 complementary pairs (4 waves) each

  for (int l = 0; l < L_; ++l) {
    int first = (l % 2 == 0);
    const unsigned short* vA = first ? valsb : xb;

    gemm_bt_bf16<<<gproj, 256, 0, stream>>>(xb, wkb + (size_t)l * D_ * D_, bk + l * D_,
                                            nullptr, qkb, (int)NTOK, D_, D_, 0);
    gemm_bt_bf16<<<gproj, 256, 0, stream>>>(vA, wvb + (size_t)l * D_ * D_, bv + l * D_,
                                            nullptr, vb, (int)NTOK, D_, D_, 0);
    transpose_heads_bf16<<<gtr, 256, 0, stream>>>(vb, vtb);
    attn_mfma3<<<gattn, 256, 0, stream>>>(qkb, vtb, gammas + l * H_, aob, first ? 0 : 1);
    gemm_bt_bf16<<<gproj, 256, 0, stream>>>(aob, wob + (size_t)l * D_ * D_, bo + l * D_,
                                            qkf, nullptr, (int)NTOK, D_, D_, 0);
    add_ln<<<(int)NTOK, 256, 0, stream>>>(x, xb, qkf, ln1_g + l * D_, ln1_b + l * D_);
    if (first) {
      gemm_bt_bf16<<<gf1, 256, 0, stream>>>(xb, w1b + (size_t)l * DFF_ * D_, b1 + l * DFF_,
                                            nullptr, ffnb, (int)NTOK, DFF_, D_, 1);
      gemm_bt_bf16<<<gf2, 256, 0, stream>>>(ffnb, w2b + (size_t)l * D_ * DFF_, b2 + l * D_,
                                            qkf, nullptr, (int)NTOK, D_, DFF_, 0);
      add_ln<<<(int)NTOK, 256, 0, stream>>>(x, xb, qkf, ln2_g + l * D_, ln2_b + l * D_);
    }
  }
}

// Round 16
// 1114.955 us; speedup vs baseline: 1.1128x; 1.0164x over previous
//
#include <hip/hip_runtime.h>
#include <hip/hip_bf16.h>
#include <math.h>

#define B_ 32
#define S_ 512
#define D_ 512
#define H_ 8
#define DK_ 64
#define DFF_ 2048
#define L_ 4

typedef __attribute__((ext_vector_type(8))) short bf16x8;
typedef __attribute__((ext_vector_type(4))) float f32x4;

__device__ __forceinline__ unsigned short f2bf(float x) {
  union { float f; unsigned u; } v; v.f = x;
  unsigned r = v.u + 0x7fff + ((v.u >> 16) & 1);   // round-nearest-even
  return (unsigned short)(r >> 16);
}

__device__ __forceinline__ unsigned short f2h(float x) {
  union { _Float16 h; unsigned short u; } v;
  v.h = (_Float16)x;
  return v.u;
}
__device__ __forceinline__ float h2f(unsigned short u) {
  union { _Float16 h; unsigned short u; } v;
  v.u = u;
  return (float)v.h;
}

// inclusive 16-lane prefix sum via DPP row_shr (VALU only). bound_ctrl -> 0-fill.
#define DPP_ADD_SHR(x, N)                                                       \
  {                                                                             \
    int _t = __builtin_amdgcn_update_dpp(0, __float_as_int(x), 0x110 + (N),     \
                                         0xf, 0xf, true);                       \
    (x) += __int_as_float(_t);                                                  \
  }
__device__ __forceinline__ float scan16_dpp(float x) {
  DPP_ADD_SHR(x, 1);
  DPP_ADD_SHR(x, 2);
  DPP_ADD_SHR(x, 4);
  DPP_ADD_SHR(x, 8);
  return x;
}
// broadcast lane (id|15)'s value to all lanes of each 16-lane row
__device__ __forceinline__ float bcast15(float x) {
  return __int_as_float(__builtin_amdgcn_ds_swizzle(__float_as_int(x), 0x1FF));
}

__device__ __forceinline__ void load_lds16(const void* g, void* l) {
  __builtin_amdgcn_global_load_lds(
      (const __attribute__((address_space(1))) void*)g,
      (__attribute__((address_space(3))) void*)l, 16, 0, 0);
}

// ---------- f32 -> bf16 convert ----------
__global__ __launch_bounds__(256) void cvt_f32_bf16(
    const float* __restrict__ in, unsigned short* __restrict__ out, size_t n8)
{
  size_t idx = (size_t)blockIdx.x * 256 + threadIdx.x;
  size_t stride = (size_t)gridDim.x * 256;
  for (size_t i = idx; i < n8; i += stride) {
    const float4* p = (const float4*)(in + i * 8);
    float4 a = p[0], b = p[1];
    union { unsigned short u[8]; int4 v; } o;
    o.u[0] = f2bf(a.x); o.u[1] = f2bf(a.y); o.u[2] = f2bf(a.z); o.u[3] = f2bf(a.w);
    o.u[4] = f2bf(b.x); o.u[5] = f2bf(b.y); o.u[6] = f2bf(b.z); o.u[7] = f2bf(b.w);
    *(int4*)(out + i * 8) = o.v;
  }
}

// ---------- copy f32 + emit bf16 ----------
__global__ __launch_bounds__(256) void copy_cvt(
    const float* __restrict__ in, float* __restrict__ outf,
    unsigned short* __restrict__ outb, size_t n8)
{
  size_t idx = (size_t)blockIdx.x * 256 + threadIdx.x;
  size_t stride = (size_t)gridDim.x * 256;
  for (size_t i = idx; i < n8; i += stride) {
    const float4* p = (const float4*)(in + i * 8);
    float4 a = p[0], b = p[1];
    ((float4*)(outf + i * 8))[0] = a;
    ((float4*)(outf + i * 8))[1] = b;
    union { unsigned short u[8]; int4 v; } o;
    o.u[0] = f2bf(a.x); o.u[1] = f2bf(a.y); o.u[2] = f2bf(a.z); o.u[3] = f2bf(a.w);
    o.u[4] = f2bf(b.x); o.u[5] = f2bf(b.y); o.u[6] = f2bf(b.z); o.u[7] = f2bf(b.w);
    *(int4*)(outb + i * 8) = o.v;
  }
}

// ---------- bf16 MFMA GEMM: C[M,N] = A[M,K] @ W[N,K]^T + bias ----------
__global__ __launch_bounds__(256) void gemm_bt_bf16(
    const unsigned short* __restrict__ A, const unsigned short* __restrict__ W,
    const float* __restrict__ bias,
    float* __restrict__ Cf, unsigned short* __restrict__ Cb,
    int M, int N, int K, int relu)
{
  __shared__ __align__(16) short As[128 * 32];
  __shared__ __align__(16) short Ws[128 * 32];
  int tid = threadIdx.x;
  int lane = tid & 63, w = tid >> 6;
  int wr = w >> 1, wc = w & 1;
  int bm = blockIdx.y * 128, bn = blockIdx.x * 128;

  f32x4 acc[4][4];
  #pragma unroll
  for (int m = 0; m < 4; ++m)
    #pragma unroll
    for (int n = 0; n < 4; ++n) acc[m][n] = (f32x4){0.f, 0.f, 0.f, 0.f};

  int srow = tid >> 2;
  int skB  = (tid & 3) * 16;
  const char* pa0 = (const char*)(A + (size_t)(bm + srow) * K) + skB;
  const char* pa1 = (const char*)(A + (size_t)(bm + 64 + srow) * K) + skB;
  const char* pw0 = (const char*)(W + (size_t)(bn + srow) * K) + skB;
  const char* pw1 = (const char*)(W + (size_t)(bn + 64 + srow) * K) + skB;
  char* lA0 = (char*)As + w * 1024;
  char* lA1 = (char*)As + 4096 + w * 1024;
  char* lW0 = (char*)Ws + w * 1024;
  char* lW1 = (char*)Ws + 4096 + w * 1024;

  int r = lane & 15, k8 = lane >> 4;
  const bf16x8* Arow = (const bf16x8*)As;
  const bf16x8* Wrow = (const bf16x8*)Ws;

  for (int k0 = 0; k0 < K; k0 += 32) {
    load_lds16(pa0, lA0);
    load_lds16(pa1, lA1);
    load_lds16(pw0, lW0);
    load_lds16(pw1, lW1);
    pa0 += 64; pa1 += 64; pw0 += 64; pw1 += 64;
    __syncthreads();
    bf16x8 aF[4], bF[4];
    #pragma unroll
    for (int m = 0; m < 4; ++m) aF[m] = Arow[(wr * 64 + m * 16 + r) * 4 + k8];
    #pragma unroll
    for (int n = 0; n < 4; ++n) bF[n] = Wrow[(wc * 64 + n * 16 + r) * 4 + k8];
    #pragma unroll
    for (int m = 0; m < 4; ++m)
      #pragma unroll
      for (int n = 0; n < 4; ++n)
        acc[m][n] = __builtin_amdgcn_mfma_f32_16x16x32_bf16(aF[m], bF[n], acc[m][n], 0, 0, 0);
    __syncthreads();
  }

  int orow0 = bm + wr * 64 + (lane >> 4) * 4;
  int ocol0 = bn + wc * 64 + (lane & 15);
  #pragma unroll
  for (int n = 0; n < 4; ++n) {
    int col = ocol0 + n * 16;
    float bv = bias[col];
    #pragma unroll
    for (int m = 0; m < 4; ++m) {
      int row = orow0 + m * 16;
      #pragma unroll
      for (int j = 0; j < 4; ++j) {
        float val = acc[m][n][j] + bv;
        if (relu) val = fmaxf(val, 0.f);
        size_t off = (size_t)(row + j) * N + col;
        if (Cf) Cf[off] = val; else Cb[off] = f2bf(val);
      }
    }
  }
}

// ---------- per-head transpose (bf16): v[b][j][h*64+d] -> vt[b][h][d][j] ----------
__global__ __launch_bounds__(256) void transpose_heads_bf16(
    const unsigned short* __restrict__ v, unsigned short* __restrict__ vt)
{
  __shared__ unsigned short t[64][65];
  int jt = blockIdx.x, h = blockIdx.y, b = blockIdx.z;
  int lane = threadIdx.x & 63, w = threadIdx.x >> 6;
  #pragma unroll
  for (int r = 0; r < 16; ++r) {
    int j = w + r * 4;
    t[j][lane] = v[((size_t)(b * S_ + jt * 64 + j)) * D_ + h * DK_ + lane];
  }
  __syncthreads();
  #pragma unroll
  for (int r = 0; r < 16; ++r) {
    int d = w + r * 4;
    vt[((size_t)((b * H_ + h) * DK_ + d)) * S_ + jt * 64 + lane] = t[lane][d];
  }
}

// ---------- R4/R7-verbatim QK tile: scores scaled + boundary-masked ----------
__device__ __forceinline__ f32x4 qk_tile(
    int kt, int qt, int i0, int g, int c15, int maskType,
    const unsigned short* kbase, bf16x8 aQ0, bf16x8 aQ1)
{
  const unsigned short* kr = kbase + (size_t)(kt * 16 + c15) * D_;
  bf16x8 bK0 = *(const bf16x8*)(kr);
  bf16x8 bK1 = *(const bf16x8*)(kr + 32);
  f32x4 c = (f32x4){0.f, 0.f, 0.f, 0.f};
  c = __builtin_amdgcn_mfma_f32_16x16x32_bf16(aQ0, bK0, c, 0, 0, 0);
  c = __builtin_amdgcn_mfma_f32_16x16x32_bf16(aQ1, bK1, c, 0, 0, 0);
  #pragma unroll
  for (int r = 0; r < 4; ++r) c[r] *= 0.125f;
  if (kt == qt) {
    int j = kt * 16 + c15;
    #pragma unroll
    for (int r = 0; r < 4; ++r) {
      int i = i0 + 4 * g + r;
      bool valid = maskType ? (j <= i) : (j < i);
      if (!valid) c[r] = -1e30f;
    }
  }
  return c;
}

// ---------- MFMA attention: complementary pairs, DPP scan, XCD-swizzled blocks ----------
// XCD swizzle (T1): dispatcher round-robins blockIdx across the 8 XCDs; remap
// so all 8 blocks sharing one (b,h) K/V panel land on ONE XCD -> its private
// L2 serves the panel instead of 8 separate HBM refetches. 2048 = 8*256 exact.
#define PSTRIDE 40
__global__ __launch_bounds__(256) void attn_mfma3(
    const unsigned short* __restrict__ qkb,   // q==k bf16 [b][s][D]
    const unsigned short* __restrict__ vtb,   // V^T bf16 [b][h][64][S]
    const float* __restrict__ gammas,
    unsigned short* __restrict__ ao,
    int maskType)
{
  __shared__ __align__(16) unsigned short scr_all[2][33 * 16][16];  // per-pair score cache
  __shared__ __align__(16) unsigned short P_all[4][16][PSTRIDE];
  int tid = threadIdx.x;
  int lane = tid & 63, w = tid >> 6;
  int hid = blockIdx.x;
  int bid = (hid & 7) * 256 + (hid >> 3);       // XCD-chunked work id (bijective)
  int pp = bid & 7;
  int h = (bid >> 3) & (H_ - 1);
  int b = bid >> 6;
  int pairIdx = w >> 1, wp = w & 1;
  int p = pp * 2 + pairIdx;                     // 0..15
  int qt = wp ? (31 - p) : p;                   // complementary pair
  int rowbase = wp ? (p + 1) * 16 : 0;
  unsigned short (*scr)[16] = &scr_all[pairIdx][rowbase];
  unsigned short (*P_lds)[PSTRIDE] = P_all[w];
  int i0 = qt * 16;
  int c15 = lane & 15, g = lane >> 4;
  int scol = 4 * ((g + (c15 >> 2)) & 3);        // bank-swizzled scr column

  const unsigned short* qbase =
      qkb + ((size_t)(b * S_ + i0 + c15)) * D_ + h * DK_ + g * 8;
  bf16x8 aQ0 = *(const bf16x8*)(qbase);
  bf16x8 aQ1 = *(const bf16x8*)(qbase + 32);
  const unsigned short* kbase = qkb + ((size_t)b * S_) * D_ + h * DK_ + g * 8;

  float gam = gammas[h];
  float gneg = -((gam > 20.f) ? gam : log1pf(__expf(gam)));   // -softplus < 0

  // ---- phase 1: QK once; f16 scores -> LDS (swizzled); running m1 ----
  float m1[4] = {-1e30f, -1e30f, -1e30f, -1e30f};
  for (int kt = 0; kt <= qt; ++kt) {
    f32x4 c = qk_tile(kt, qt, i0, g, c15, maskType, kbase, aQ0, aQ1);
    int j = kt * 16 + c15;
    int lo = (int)f2h(c[0]) | ((int)f2h(c[1]) << 16);
    int hi = (int)f2h(c[2]) | ((int)f2h(c[3]) << 16);
    *(int2*)&scr[j][scol] = make_int2(lo, hi);
    #pragma unroll
    for (int r = 0; r < 4; ++r) m1[r] = fmaxf(m1[r], c[r]);
  }
  #pragma unroll
  for (int r = 0; r < 4; ++r)
    #pragma unroll
    for (int off = 1; off < 16; off <<= 1)
      m1[r] = fmaxf(m1[r], __shfl_xor(m1[r], off, 64));
  // no fence: phase-2 reads are same-lane addresses; DS per-wave is in-order
  // and the compiler orders may-aliasing LDS accesses + inserts lgkmcnt.

  // ---- phase 2: sum1 from LDS scores (fixed m1) ----
  float sum1[4] = {0.f, 0.f, 0.f, 0.f};
  for (int kt = 0; kt <= qt; ++kt) {
    int j = kt * 16 + c15;
    int2 d = *(const int2*)&scr[j][scol];
    float s0 = h2f((unsigned short)(d.x & 0xffff));
    float s1 = h2f((unsigned short)((unsigned)d.x >> 16));
    float s2_ = h2f((unsigned short)(d.y & 0xffff));
    float s3 = h2f((unsigned short)((unsigned)d.y >> 16));
    sum1[0] += __expf(s0 - m1[0]);
    sum1[1] += __expf(s1 - m1[1]);
    sum1[2] += __expf(s2_ - m1[2]);
    sum1[3] += __expf(s3 - m1[3]);
  }
  #pragma unroll
  for (int r = 0; r < 4; ++r)
    #pragma unroll
    for (int off = 1; off < 16; off <<= 1)
      sum1[r] += __shfl_xor(sum1[r], off, 64);
  float inv1[4], m2b[4];
  #pragma unroll
  for (int r = 0; r < 4; ++r) {
    inv1[r] = (sum1[r] > 0.f) ? 1.f / sum1[r] : 0.f;
    m2b[r] = fmaxf(m1[r], 0.f);
  }

  // ---- phase 3: DPP cumsum + decay + rescore + P + fused PV ----
  f32x4 acc[4];
  #pragma unroll
  for (int dt = 0; dt < 4; ++dt) acc[dt] = (f32x4){0.f, 0.f, 0.f, 0.f};
  float sum2[4] = {0.f, 0.f, 0.f, 0.f};
  {
    float carry[4] = {0.f, 0.f, 0.f, 0.f};
    const unsigned short* vbase =
        vtb + (((size_t)(b * H_ + h) * DK_) + c15) * S_ + g * 8;

    #pragma unroll
    for (int jc = 0; jc < 16; ++jc) {
      if (jc * 2 <= qt) {
        #pragma unroll
        for (int t2 = 0; t2 < 2; ++t2) {
          int kt = jc * 2 + t2;
          if (kt <= qt) {
            int j = kt * 16 + c15;
            int2 d = *(const int2*)&scr[j][scol];
            float sv[4];
            sv[0] = h2f((unsigned short)(d.x & 0xffff));
            sv[1] = h2f((unsigned short)((unsigned)d.x >> 16));
            sv[2] = h2f((unsigned short)(d.y & 0xffff));
            sv[3] = h2f((unsigned short)((unsigned)d.y >> 16));
            #pragma unroll
            for (int r = 0; r < 4; ++r) {
              float e = __expf(sv[r] - m1[r]);
              float p2 = scan16_dpp(e);           // inclusive scan over c15
              float tot = bcast15(p2);            // row total (lane|15)
              float cum = carry[r] + p2;
              carry[r] += tot;
              float suffix = sum1[r] - cum;
              int i = i0 + 4 * g + r;
              float pos = fabsf((float)(kt * 16 + c15 - i));
              float dist = sqrtf(fmaxf(suffix * inv1[r] * pos, 0.f));
              float te = fminf(fmaxf(__expf(dist * gneg), 1e-5f), 1e5f);
              float s2 = sv[r] * te;
              float e2 = __expf(s2 - m2b[r]);
              sum2[r] += e2;
              P_lds[4 * g + r][t2 * 16 + c15] = f2bf(e2);
            }
          } else {
            #pragma unroll
            for (int r = 0; r < 4; ++r) P_lds[4 * g + r][t2 * 16 + c15] = 0;
          }
        }
        // no explicit fence: all lanes issue P writes before the P read
        // (single instruction stream), DS per-wave is in-order, and the
        // compiler's alias analysis orders the LDS ops + inserts lgkmcnt.
        bf16x8 aP = *(const bf16x8*)&P_lds[c15][g * 8];
        const unsigned short* vr = vbase + (size_t)jc * 32;
        #pragma unroll
        for (int dt = 0; dt < 4; ++dt) {
          bf16x8 bV = *(const bf16x8*)(vr + (size_t)dt * 16 * S_);
          acc[dt] = __builtin_amdgcn_mfma_f32_16x16x32_bf16(aP, bV, acc[dt], 0, 0, 0);
        }
      }
    }
  }
  #pragma unroll
  for (int r = 0; r < 4; ++r)
    #pragma unroll
    for (int off = 1; off < 16; off <<= 1)
      sum2[r] += __shfl_xor(sum2[r], off, 64);

  // ---- epilogue: normalize (guarded), zeroPad row0, store bf16 ----
  int zp = (maskType == 0 && qt == 0);
  #pragma unroll
  for (int dt = 0; dt < 4; ++dt) {
    #pragma unroll
    for (int r = 0; r < 4; ++r) {
      int i = i0 + 4 * g + r;
      float ns = (sum2[r] > 0.f) ? 1.f / sum2[r] : 0.f;
      float val = acc[dt][r] * ns;
      if (zp && (4 * g + r) == 0) val = 0.f;
      ao[((size_t)(b * S_ + i)) * D_ + h * DK_ + dt * 16 + c15] = f2bf(val);
    }
  }
}

// ---------- wave/block reduce + residual LN (also emits bf16 x) ----------
__device__ __forceinline__ float blockReduceSum256(float v, float* red) {
  #pragma unroll
  for (int off = 32; off > 0; off >>= 1) v += __shfl_down(v, off, 64);
  int lane = threadIdx.x & 63, wid = threadIdx.x >> 6;
  __syncthreads();
  if (lane == 0) red[wid] = v;
  __syncthreads();
  return red[0] + red[1] + red[2] + red[3];
}

__global__ __launch_bounds__(256) void add_ln(
    float* __restrict__ x, unsigned short* __restrict__ xb,
    const float* __restrict__ r,
    const float* __restrict__ g, const float* __restrict__ b)
{
  int row = blockIdx.x;
  int t = threadIdx.x;
  float* xr = x + (size_t)row * D_;
  unsigned short* xbr = xb + (size_t)row * D_;
  const float* rr = r + (size_t)row * D_;
  float v0 = xr[t] + rr[t];
  float v1 = xr[t + 256] + rr[t + 256];
  __shared__ float red[4];
  float s = blockReduceSum256(v0 + v1, red);
  float mu = s * (1.0f / 512.0f);
  float d0 = v0 - mu, d1 = v1 - mu;
  float sq = blockReduceSum256(d0 * d0 + d1 * d1, red);
  float rstd = rsqrtf(sq * (1.0f / 512.0f) + 1e-5f);
  float o0 = d0 * rstd * g[t] + b[t];
  float o1 = d1 * rstd * g[t + 256] + b[t + 256];
  xr[t] = o0;
  xr[t + 256] = o1;
  xbr[t] = f2bf(o0);
  xbr[t + 256] = f2bf(o1);
}

static inline void cvt(const float* in, unsigned short* out, size_t n, hipStream_t s) {
  size_t n8 = n / 8;
  int blocks = (int)((n8 + 255) / 256);
  if (blocks > 2048) blocks = 2048;
  cvt_f32_bf16<<<blocks, 256, 0, s>>>(in, out, n8);
}

extern "C" void kernel_launch(void* const* d_in, const int* in_sizes, int n_in,
                              void* d_out, int out_size, void* d_ws, size_t ws_size,
                              hipStream_t stream) {
  const float* q_embed  = (const float*)d_in[0];
  const float* qa_embed = (const float*)d_in[1];
  const float* Wk = (const float*)d_in[2];
  const float* bk = (const float*)d_in[3];
  const float* Wv = (const float*)d_in[4];
  const float* bv = (const float*)d_in[5];
  const float* Wo = (const float*)d_in[6];
  const float* bo = (const float*)d_in[7];
  const float* gammas = (const float*)d_in[8];
  const float* ln1_g = (const float*)d_in[9];
  const float* ln1_b = (const float*)d_in[10];
  const float* W1 = (const float*)d_in[11];
  const float* b1 = (const float*)d_in[12];
  const float* W2 = (const float*)d_in[13];
  const float* b2 = (const float*)d_in[14];
  const float* ln2_g = (const float*)d_in[15];
  const float* ln2_b = (const float*)d_in[16];

  float* x = (float*)d_out;
  const size_t NTOK = (size_t)B_ * S_;      // 16384
  const size_t ND = NTOK * D_;

  float* qkf = (float*)d_ws;                               // f32 scratch [ND]
  unsigned short* xb    = (unsigned short*)(qkf + ND);     // bf16 [ND]
  unsigned short* valsb = xb + ND;
  unsigned short* qkb   = valsb + ND;
  unsigned short* vb    = qkb + ND;
  unsigned short* vtb   = vb + ND;
  unsigned short* aob   = vtb + ND;
  unsigned short* wkb   = aob + ND;
  unsigned short* wvb   = wkb + (size_t)L_ * D_ * D_;
  unsigned short* wob   = wvb + (size_t)L_ * D_ * D_;
  unsigned short* w1b   = wob + (size_t)L_ * D_ * D_;
  unsigned short* w2b   = w1b + (size_t)L_ * DFF_ * D_;
  unsigned short* ffnb  = qkb;   // [NTOK*DFF] aliases qkb+vb+vtb+aob (dead in FFN phase)

  // x (f32) + xb (bf16) from q_embed in one pass
  {
    size_t n8 = ND / 8;
    copy_cvt<<<2048, 256, 0, stream>>>(q_embed, x, xb, n8);
  }

  cvt(Wk, wkb, (size_t)L_ * D_ * D_, stream);
  cvt(Wv, wvb, (size_t)L_ * D_ * D_, stream);
  cvt(Wo, wob, (size_t)L_ * D_ * D_, stream);
  cvt(W1, w1b, (size_t)L_ * DFF_ * D_, stream);
  cvt(W2, w2b, (size_t)L_ * DFF_ * D_, stream);
  cvt(qa_embed, valsb, ND, stream);

  dim3 gproj(D_ / 128, NTOK / 128);
  dim3 gf1(DFF_ / 128, NTOK / 128);
  dim3 gf2(D_ / 128, NTOK / 128);
  dim3 gtr(S_ / 64, H_, B_);
  int gattn = B_ * H_ * 8;   // 2048 blocks, 2 complementary pairs (4 waves) each

  for (int l = 0; l < L_; ++l) {
    int first = (l % 2 == 0);
    const unsigned short* vA = first ? valsb : xb;

    gemm_bt_bf16<<<gproj, 256, 0, stream>>>(xb, wkb + (size_t)l * D_ * D_, bk + l * D_,
                                            nullptr, qkb, (int)NTOK, D_, D_, 0);
    gemm_bt_bf16<<<gproj, 256, 0, stream>>>(vA, wvb + (size_t)l * D_ * D_, bv + l * D_,
                                            nullptr, vb, (int)NTOK, D_, D_, 0);
    transpose_heads_bf16<<<gtr, 256, 0, stream>>>(vb, vtb);
    attn_mfma3<<<gattn, 256, 0, stream>>>(qkb, vtb, gammas + l * H_, aob, first ? 0 : 1);
    gemm_bt_bf16<<<gproj, 256, 0, stream>>>(aob, wob + (size_t)l * D_ * D_, bo + l * D_,
                                            qkf, nullptr, (int)NTOK, D_, D_, 0);
    add_ln<<<(int)NTOK, 256, 0, stream>>>(x, xb, qkf, ln1_g + l * D_, ln1_b + l * D_);
    if (first) {
      gemm_bt_bf16<<<gf1, 256, 0, stream>>>(xb, w1b + (size_t)l * DFF_ * D_, b1 + l * DFF_,
                                            nullptr, ffnb, (int)NTOK, DFF_, D_, 1);
      gemm_bt_bf16<<<gf2, 256, 0, stream>>>(ffnb, w2b + (size_t)l * D_ * DFF_, b2 + l * D_,
                                            qkf, nullptr, (int)NTOK, D_, DFF_, 0);
      add_ln<<<(int)NTOK, 256, 0, stream>>>(x, xb, qkf, ln2_g + l * D_, ln2_b + l * D_);
    }
  }
}

// Round 17
// 1097.895 us; speedup vs baseline: 1.1301x; 1.0155x over previous
//
#include <hip/hip_runtime.h>
#include <hip/hip_bf16.h>
#include <math.h>

#define B_ 32
#define S_ 512
#define D_ 512
#define H_ 8
#define DK_ 64
#define DFF_ 2048
#define L_ 4

typedef __attribute__((ext_vector_type(8))) short bf16x8;
typedef __attribute__((ext_vector_type(4))) float f32x4;

__device__ __forceinline__ unsigned short f2bf(float x) {
  union { float f; unsigned u; } v; v.f = x;
  unsigned r = v.u + 0x7fff + ((v.u >> 16) & 1);   // round-nearest-even
  return (unsigned short)(r >> 16);
}

__device__ __forceinline__ unsigned short f2h(float x) {
  union { _Float16 h; unsigned short u; } v;
  v.h = (_Float16)x;
  return v.u;
}
__device__ __forceinline__ float h2f(unsigned short u) {
  union { _Float16 h; unsigned short u; } v;
  v.u = u;
  return (float)v.h;
}

// inclusive 16-lane prefix sum via DPP row_shr (VALU only). bound_ctrl -> 0-fill.
#define DPP_ADD_SHR(x, N)                                                       \
  {                                                                             \
    int _t = __builtin_amdgcn_update_dpp(0, __float_as_int(x), 0x110 + (N),     \
                                         0xf, 0xf, true);                       \
    (x) += __int_as_float(_t);                                                  \
  }
__device__ __forceinline__ float scan16_dpp(float x) {
  DPP_ADD_SHR(x, 1);
  DPP_ADD_SHR(x, 2);
  DPP_ADD_SHR(x, 4);
  DPP_ADD_SHR(x, 8);
  return x;
}
// broadcast lane (id|15)'s value to all lanes of each 16-lane row
__device__ __forceinline__ float bcast15(float x) {
  return __int_as_float(__builtin_amdgcn_ds_swizzle(__float_as_int(x), 0x1FF));
}

__device__ __forceinline__ void load_lds16(const void* g, void* l) {
  __builtin_amdgcn_global_load_lds(
      (const __attribute__((address_space(1))) void*)g,
      (__attribute__((address_space(3))) void*)l, 16, 0, 0);
}

// ---------- f32 -> bf16 convert ----------
__global__ __launch_bounds__(256) void cvt_f32_bf16(
    const float* __restrict__ in, unsigned short* __restrict__ out, size_t n8)
{
  size_t idx = (size_t)blockIdx.x * 256 + threadIdx.x;
  size_t stride = (size_t)gridDim.x * 256;
  for (size_t i = idx; i < n8; i += stride) {
    const float4* p = (const float4*)(in + i * 8);
    float4 a = p[0], b = p[1];
    union { unsigned short u[8]; int4 v; } o;
    o.u[0] = f2bf(a.x); o.u[1] = f2bf(a.y); o.u[2] = f2bf(a.z); o.u[3] = f2bf(a.w);
    o.u[4] = f2bf(b.x); o.u[5] = f2bf(b.y); o.u[6] = f2bf(b.z); o.u[7] = f2bf(b.w);
    *(int4*)(out + i * 8) = o.v;
  }
}

// ---------- copy f32 + emit bf16 ----------
__global__ __launch_bounds__(256) void copy_cvt(
    const float* __restrict__ in, float* __restrict__ outf,
    unsigned short* __restrict__ outb, size_t n8)
{
  size_t idx = (size_t)blockIdx.x * 256 + threadIdx.x;
  size_t stride = (size_t)gridDim.x * 256;
  for (size_t i = idx; i < n8; i += stride) {
    const float4* p = (const float4*)(in + i * 8);
    float4 a = p[0], b = p[1];
    ((float4*)(outf + i * 8))[0] = a;
    ((float4*)(outf + i * 8))[1] = b;
    union { unsigned short u[8]; int4 v; } o;
    o.u[0] = f2bf(a.x); o.u[1] = f2bf(a.y); o.u[2] = f2bf(a.z); o.u[3] = f2bf(a.w);
    o.u[4] = f2bf(b.x); o.u[5] = f2bf(b.y); o.u[6] = f2bf(b.z); o.u[7] = f2bf(b.w);
    *(int4*)(outb + i * 8) = o.v;
  }
}

// ---------- bf16 MFMA GEMM: C[M,N] = A[M,K] @ W[N,K]^T + bias ----------
__global__ __launch_bounds__(256) void gemm_bt_bf16(
    const unsigned short* __restrict__ A, const unsigned short* __restrict__ W,
    const float* __restrict__ bias,
    float* __restrict__ Cf, unsigned short* __restrict__ Cb,
    int M, int N, int K, int relu)
{
  __shared__ __align__(16) short As[128 * 32];
  __shared__ __align__(16) short Ws[128 * 32];
  int tid = threadIdx.x;
  int lane = tid & 63, w = tid >> 6;
  int wr = w >> 1, wc = w & 1;
  int bm = blockIdx.y * 128, bn = blockIdx.x * 128;

  f32x4 acc[4][4];
  #pragma unroll
  for (int m = 0; m < 4; ++m)
    #pragma unroll
    for (int n = 0; n < 4; ++n) acc[m][n] = (f32x4){0.f, 0.f, 0.f, 0.f};

  int srow = tid >> 2;
  int skB  = (tid & 3) * 16;
  const char* pa0 = (const char*)(A + (size_t)(bm + srow) * K) + skB;
  const char* pa1 = (const char*)(A + (size_t)(bm + 64 + srow) * K) + skB;
  const char* pw0 = (const char*)(W + (size_t)(bn + srow) * K) + skB;
  const char* pw1 = (const char*)(W + (size_t)(bn + 64 + srow) * K) + skB;
  char* lA0 = (char*)As + w * 1024;
  char* lA1 = (char*)As + 4096 + w * 1024;
  char* lW0 = (char*)Ws + w * 1024;
  char* lW1 = (char*)Ws + 4096 + w * 1024;

  int r = lane & 15, k8 = lane >> 4;
  const bf16x8* Arow = (const bf16x8*)As;
  const bf16x8* Wrow = (const bf16x8*)Ws;

  for (int k0 = 0; k0 < K; k0 += 32) {
    load_lds16(pa0, lA0);
    load_lds16(pa1, lA1);
    load_lds16(pw0, lW0);
    load_lds16(pw1, lW1);
    pa0 += 64; pa1 += 64; pw0 += 64; pw1 += 64;
    __syncthreads();
    bf16x8 aF[4], bF[4];
    #pragma unroll
    for (int m = 0; m < 4; ++m) aF[m] = Arow[(wr * 64 + m * 16 + r) * 4 + k8];
    #pragma unroll
    for (int n = 0; n < 4; ++n) bF[n] = Wrow[(wc * 64 + n * 16 + r) * 4 + k8];
    #pragma unroll
    for (int m = 0; m < 4; ++m)
      #pragma unroll
      for (int n = 0; n < 4; ++n)
        acc[m][n] = __builtin_amdgcn_mfma_f32_16x16x32_bf16(aF[m], bF[n], acc[m][n], 0, 0, 0);
    __syncthreads();
  }

  int orow0 = bm + wr * 64 + (lane >> 4) * 4;
  int ocol0 = bn + wc * 64 + (lane & 15);
  #pragma unroll
  for (int n = 0; n < 4; ++n) {
    int col = ocol0 + n * 16;
    float bv = bias[col];
    #pragma unroll
    for (int m = 0; m < 4; ++m) {
      int row = orow0 + m * 16;
      #pragma unroll
      for (int j = 0; j < 4; ++j) {
        float val = acc[m][n][j] + bv;
        if (relu) val = fmaxf(val, 0.f);
        size_t off = (size_t)(row + j) * N + col;
        if (Cf) Cf[off] = val; else Cb[off] = f2bf(val);
      }
    }
  }
}

// ---------- per-head transpose (bf16): v[b][j][h*64+d] -> vt[b][h][d][j] ----------
__global__ __launch_bounds__(256) void transpose_heads_bf16(
    const unsigned short* __restrict__ v, unsigned short* __restrict__ vt)
{
  __shared__ unsigned short t[64][65];
  int jt = blockIdx.x, h = blockIdx.y, b = blockIdx.z;
  int lane = threadIdx.x & 63, w = threadIdx.x >> 6;
  #pragma unroll
  for (int r = 0; r < 16; ++r) {
    int j = w + r * 4;
    t[j][lane] = v[((size_t)(b * S_ + jt * 64 + j)) * D_ + h * DK_ + lane];
  }
  __syncthreads();
  #pragma unroll
  for (int r = 0; r < 16; ++r) {
    int d = w + r * 4;
    vt[((size_t)((b * H_ + h) * DK_ + d)) * S_ + jt * 64 + lane] = t[lane][d];
  }
}

// ---------- MFMA attention: complementary pairs, DPP scan, XCD swizzle,
// ---------- depth-1 software pipelining in phases 1 and 3 ----------
#define PSTRIDE 40
__global__ __launch_bounds__(256) void attn_mfma3(
    const unsigned short* __restrict__ qkb,   // q==k bf16 [b][s][D]
    const unsigned short* __restrict__ vtb,   // V^T bf16 [b][h][64][S]
    const float* __restrict__ gammas,
    unsigned short* __restrict__ ao,
    int maskType)
{
  __shared__ __align__(16) unsigned short scr_all[2][33 * 16][16];  // per-pair score cache
  __shared__ __align__(16) unsigned short P_all[4][16][PSTRIDE];
  int tid = threadIdx.x;
  int lane = tid & 63, w = tid >> 6;
  int hid = blockIdx.x;
  int bid = (hid & 7) * 256 + (hid >> 3);       // XCD-chunked work id (bijective)
  int pp = bid & 7;
  int h = (bid >> 3) & (H_ - 1);
  int b = bid >> 6;
  int pairIdx = w >> 1, wp = w & 1;
  int p = pp * 2 + pairIdx;                     // 0..15
  int qt = wp ? (31 - p) : p;                   // complementary pair
  int rowbase = wp ? (p + 1) * 16 : 0;
  unsigned short (*scr)[16] = &scr_all[pairIdx][rowbase];
  unsigned short (*P_lds)[PSTRIDE] = P_all[w];
  int i0 = qt * 16;
  int c15 = lane & 15, g = lane >> 4;
  int scol = 4 * ((g + (c15 >> 2)) & 3);        // bank-swizzled scr column

  const unsigned short* qbase =
      qkb + ((size_t)(b * S_ + i0 + c15)) * D_ + h * DK_ + g * 8;
  bf16x8 aQ0 = *(const bf16x8*)(qbase);
  bf16x8 aQ1 = *(const bf16x8*)(qbase + 32);
  const unsigned short* kbase = qkb + ((size_t)b * S_) * D_ + h * DK_ + g * 8;

  float gam = gammas[h];
  float gneg = -((gam > 20.f) ? gam : log1pf(__expf(gam)));   // -softplus < 0

  // ---- phase 1: QK once (K prefetched 1 tile ahead); scores -> LDS; m1 ----
  float m1[4] = {-1e30f, -1e30f, -1e30f, -1e30f};
  {
    const unsigned short* kr0 = kbase + (size_t)c15 * D_;
    bf16x8 nK0 = *(const bf16x8*)(kr0);
    bf16x8 nK1 = *(const bf16x8*)(kr0 + 32);
    for (int kt = 0; kt <= qt; ++kt) {
      bf16x8 cK0 = nK0, cK1 = nK1;
      if (kt < qt) {
        const unsigned short* nkr = kbase + (size_t)((kt + 1) * 16 + c15) * D_;
        nK0 = *(const bf16x8*)(nkr);
        nK1 = *(const bf16x8*)(nkr + 32);
      }
      f32x4 c = (f32x4){0.f, 0.f, 0.f, 0.f};
      c = __builtin_amdgcn_mfma_f32_16x16x32_bf16(aQ0, cK0, c, 0, 0, 0);
      c = __builtin_amdgcn_mfma_f32_16x16x32_bf16(aQ1, cK1, c, 0, 0, 0);
      #pragma unroll
      for (int r = 0; r < 4; ++r) c[r] *= 0.125f;
      if (kt == qt) {
        int j = kt * 16 + c15;
        #pragma unroll
        for (int r = 0; r < 4; ++r) {
          int i = i0 + 4 * g + r;
          bool valid = maskType ? (j <= i) : (j < i);
          if (!valid) c[r] = -1e30f;
        }
      }
      int j = kt * 16 + c15;
      int lo = (int)f2h(c[0]) | ((int)f2h(c[1]) << 16);
      int hi = (int)f2h(c[2]) | ((int)f2h(c[3]) << 16);
      *(int2*)&scr[j][scol] = make_int2(lo, hi);
      #pragma unroll
      for (int r = 0; r < 4; ++r) m1[r] = fmaxf(m1[r], c[r]);
    }
  }
  #pragma unroll
  for (int r = 0; r < 4; ++r)
    #pragma unroll
    for (int off = 1; off < 16; off <<= 1)
      m1[r] = fmaxf(m1[r], __shfl_xor(m1[r], off, 64));

  // ---- phase 2: sum1 from LDS scores (fixed m1) ----
  float sum1[4] = {0.f, 0.f, 0.f, 0.f};
  for (int kt = 0; kt <= qt; ++kt) {
    int j = kt * 16 + c15;
    int2 d = *(const int2*)&scr[j][scol];
    float s0 = h2f((unsigned short)(d.x & 0xffff));
    float s1 = h2f((unsigned short)((unsigned)d.x >> 16));
    float s2_ = h2f((unsigned short)(d.y & 0xffff));
    float s3 = h2f((unsigned short)((unsigned)d.y >> 16));
    sum1[0] += __expf(s0 - m1[0]);
    sum1[1] += __expf(s1 - m1[1]);
    sum1[2] += __expf(s2_ - m1[2]);
    sum1[3] += __expf(s3 - m1[3]);
  }
  #pragma unroll
  for (int r = 0; r < 4; ++r)
    #pragma unroll
    for (int off = 1; off < 16; off <<= 1)
      sum1[r] += __shfl_xor(sum1[r], off, 64);
  float inv1[4], m2b[4];
  #pragma unroll
  for (int r = 0; r < 4; ++r) {
    inv1[r] = (sum1[r] > 0.f) ? 1.f / sum1[r] : 0.f;
    m2b[r] = fmaxf(m1[r], 0.f);
  }

  // ---- phase 3: pipelined windows (scr + V prefetched 1 window ahead) ----
  f32x4 acc[4];
  #pragma unroll
  for (int dt = 0; dt < 4; ++dt) acc[dt] = (f32x4){0.f, 0.f, 0.f, 0.f};
  float sum2[4] = {0.f, 0.f, 0.f, 0.f};
  {
    float carry[4] = {0.f, 0.f, 0.f, 0.f};
    const unsigned short* vbase =
        vtb + (((size_t)(b * H_ + h) * DK_) + c15) * S_ + g * 8;
    int nwin = (qt >> 1) + 1;

    // prefetch window 0 (rows clamped to valid range; garbage discarded)
    int rB = (1 <= qt ? 1 : qt);
    int2 dA = *(const int2*)&scr[c15][scol];
    int2 dB = *(const int2*)&scr[rB * 16 + c15][scol];
    bf16x8 nV0 = *(const bf16x8*)(vbase);
    bf16x8 nV1 = *(const bf16x8*)(vbase + 16 * S_);
    bf16x8 nV2 = *(const bf16x8*)(vbase + 32 * S_);
    bf16x8 nV3 = *(const bf16x8*)(vbase + 48 * S_);

    for (int jc = 0; jc < nwin; ++jc) {
      int2 cdA = dA, cdB = dB;
      bf16x8 cV0 = nV0, cV1 = nV1, cV2 = nV2, cV3 = nV3;
      if (jc + 1 < nwin) {
        int ktA = (jc + 1) * 2;
        int ktB = (ktA + 1 <= qt) ? (ktA + 1) : qt;
        dA = *(const int2*)&scr[ktA * 16 + c15][scol];
        dB = *(const int2*)&scr[ktB * 16 + c15][scol];
        const unsigned short* vrn = vbase + (size_t)(jc + 1) * 32;
        nV0 = *(const bf16x8*)(vrn);
        nV1 = *(const bf16x8*)(vrn + 16 * S_);
        nV2 = *(const bf16x8*)(vrn + 32 * S_);
        nV3 = *(const bf16x8*)(vrn + 48 * S_);
      }
      // t2 = 0: kt = 2*jc (always valid within nwin)
      {
        int kt = jc * 2;
        float sv[4];
        sv[0] = h2f((unsigned short)(cdA.x & 0xffff));
        sv[1] = h2f((unsigned short)((unsigned)cdA.x >> 16));
        sv[2] = h2f((unsigned short)(cdA.y & 0xffff));
        sv[3] = h2f((unsigned short)((unsigned)cdA.y >> 16));
        #pragma unroll
        for (int r = 0; r < 4; ++r) {
          float e = __expf(sv[r] - m1[r]);
          float p2 = scan16_dpp(e);
          float tot = bcast15(p2);
          float cum = carry[r] + p2;
          carry[r] += tot;
          float suffix = sum1[r] - cum;
          int i = i0 + 4 * g + r;
          float pos = fabsf((float)(kt * 16 + c15 - i));
          float dist = sqrtf(fmaxf(suffix * inv1[r] * pos, 0.f));
          float te = fminf(fmaxf(__expf(dist * gneg), 1e-5f), 1e5f);
          float s2 = sv[r] * te;
          float e2 = __expf(s2 - m2b[r]);
          sum2[r] += e2;
          P_lds[4 * g + r][c15] = f2bf(e2);
        }
      }
      // t2 = 1: kt = 2*jc + 1 (may exceed qt)
      {
        int kt = jc * 2 + 1;
        if (kt <= qt) {
          float sv[4];
          sv[0] = h2f((unsigned short)(cdB.x & 0xffff));
          sv[1] = h2f((unsigned short)((unsigned)cdB.x >> 16));
          sv[2] = h2f((unsigned short)(cdB.y & 0xffff));
          sv[3] = h2f((unsigned short)((unsigned)cdB.y >> 16));
          #pragma unroll
          for (int r = 0; r < 4; ++r) {
            float e = __expf(sv[r] - m1[r]);
            float p2 = scan16_dpp(e);
            float tot = bcast15(p2);
            float cum = carry[r] + p2;
            carry[r] += tot;
            float suffix = sum1[r] - cum;
            int i = i0 + 4 * g + r;
            float pos = fabsf((float)(kt * 16 + c15 - i));
            float dist = sqrtf(fmaxf(suffix * inv1[r] * pos, 0.f));
            float te = fminf(fmaxf(__expf(dist * gneg), 1e-5f), 1e5f);
            float s2 = sv[r] * te;
            float e2 = __expf(s2 - m2b[r]);
            sum2[r] += e2;
            P_lds[4 * g + r][16 + c15] = f2bf(e2);
          }
        } else {
          #pragma unroll
          for (int r = 0; r < 4; ++r) P_lds[4 * g + r][16 + c15] = 0;
        }
      }
      // P exchange + PV MFMA (same-wave LDS; compiler orders + inserts lgkmcnt)
      bf16x8 aP = *(const bf16x8*)&P_lds[c15][g * 8];
      acc[0] = __builtin_amdgcn_mfma_f32_16x16x32_bf16(aP, cV0, acc[0], 0, 0, 0);
      acc[1] = __builtin_amdgcn_mfma_f32_16x16x32_bf16(aP, cV1, acc[1], 0, 0, 0);
      acc[2] = __builtin_amdgcn_mfma_f32_16x16x32_bf16(aP, cV2, acc[2], 0, 0, 0);
      acc[3] = __builtin_amdgcn_mfma_f32_16x16x32_bf16(aP, cV3, acc[3], 0, 0, 0);
    }
  }
  #pragma unroll
  for (int r = 0; r < 4; ++r)
    #pragma unroll
    for (int off = 1; off < 16; off <<= 1)
      sum2[r] += __shfl_xor(sum2[r], off, 64);

  // ---- epilogue: normalize (guarded), zeroPad row0, store bf16 ----
  int zp = (maskType == 0 && qt == 0);
  #pragma unroll
  for (int dt = 0; dt < 4; ++dt) {
    #pragma unroll
    for (int r = 0; r < 4; ++r) {
      int i = i0 + 4 * g + r;
      float ns = (sum2[r] > 0.f) ? 1.f / sum2[r] : 0.f;
      float val = acc[dt][r] * ns;
      if (zp && (4 * g + r) == 0) val = 0.f;
      ao[((size_t)(b * S_ + i)) * D_ + h * DK_ + dt * 16 + c15] = f2bf(val);
    }
  }
}

// ---------- wave/block reduce + residual LN (also emits bf16 x) ----------
__device__ __forceinline__ float blockReduceSum256(float v, float* red) {
  #pragma unroll
  for (int off = 32; off > 0; off >>= 1) v += __shfl_down(v, off, 64);
  int lane = threadIdx.x & 63, wid = threadIdx.x >> 6;
  __syncthreads();
  if (lane == 0) red[wid] = v;
  __syncthreads();
  return red[0] + red[1] + red[2] + red[3];
}

__global__ __launch_bounds__(256) void add_ln(
    float* __restrict__ x, unsigned short* __restrict__ xb,
    const float* __restrict__ r,
    const float* __restrict__ g, const float* __restrict__ b)
{
  int row = blockIdx.x;
  int t = threadIdx.x;
  float* xr = x + (size_t)row * D_;
  unsigned short* xbr = xb + (size_t)row * D_;
  const float* rr = r + (size_t)row * D_;
  float v0 = xr[t] + rr[t];
  float v1 = xr[t + 256] + rr[t + 256];
  __shared__ float red[4];
  float s = blockReduceSum256(v0 + v1, red);
  float mu = s * (1.0f / 512.0f);
  float d0 = v0 - mu, d1 = v1 - mu;
  float sq = blockReduceSum256(d0 * d0 + d1 * d1, red);
  float rstd = rsqrtf(sq * (1.0f / 512.0f) + 1e-5f);
  float o0 = d0 * rstd * g[t] + b[t];
  float o1 = d1 * rstd * g[t + 256] + b[t + 256];
  xr[t] = o0;
  xr[t + 256] = o1;
  xbr[t] = f2bf(o0);
  xbr[t + 256] = f2bf(o1);
}

static inline void cvt(const float* in, unsigned short* out, size_t n, hipStream_t s) {
  size_t n8 = n / 8;
  int blocks = (int)((n8 + 255) / 256);
  if (blocks > 2048) blocks = 2048;
  cvt_f32_bf16<<<blocks, 256, 0, s>>>(in, out, n8);
}

extern "C" void kernel_launch(void* const* d_in, const int* in_sizes, int n_in,
                              void* d_out, int out_size, void* d_ws, size_t ws_size,
                              hipStream_t stream) {
  const float* q_embed  = (const float*)d_in[0];
  const float* qa_embed = (const float*)d_in[1];
  const float* Wk = (const float*)d_in[2];
  const float* bk = (const float*)d_in[3];
  const float* Wv = (const float*)d_in[4];
  const float* bv = (const float*)d_in[5];
  const float* Wo = (const float*)d_in[6];
  const float* bo = (const float*)d_in[7];
  const float* gammas = (const float*)d_in[8];
  const float* ln1_g = (const float*)d_in[9];
  const float* ln1_b = (const float*)d_in[10];
  const float* W1 = (const float*)d_in[11];
  const float* b1 = (const float*)d_in[12];
  const float* W2 = (const float*)d_in[13];
  const float* b2 = (const float*)d_in[14];
  const float* ln2_g = (const float*)d_in[15];
  const float* ln2_b = (const float*)d_in[16];

  float* x = (float*)d_out;
  const size_t NTOK = (size_t)B_ * S_;      // 16384
  const size_t ND = NTOK * D_;

  float* qkf = (float*)d_ws;                               // f32 scratch [ND]
  unsigned short* xb    = (unsigned short*)(qkf + ND);     // bf16 [ND]
  unsigned short* valsb = xb + ND;
  unsigned short* qkb   = valsb + ND;
  unsigned short* vb    = qkb + ND;
  unsigned short* vtb   = vb + ND;
  unsigned short* aob   = vtb + ND;
  unsigned short* wkb   = aob + ND;
  unsigned short* wvb   = wkb + (size_t)L_ * D_ * D_;
  unsigned short* wob   = wvb + (size_t)L_ * D_ * D_;
  unsigned short* w1b   = wob + (size_t)L_ * D_ * D_;
  unsigned short* w2b   = w1b + (size_t)L_ * DFF_ * D_;
  unsigned short* ffnb  = qkb;   // [NTOK*DFF] aliases qkb+vb+vtb+aob (dead in FFN phase)

  // x (f32) + xb (bf16) from q_embed in one pass
  {
    size_t n8 = ND / 8;
    copy_cvt<<<2048, 256, 0, stream>>>(q_embed, x, xb, n8);
  }

  cvt(Wk, wkb, (size_t)L_ * D_ * D_, stream);
  cvt(Wv, wvb, (size_t)L_ * D_ * D_, stream);
  cvt(Wo, wob, (size_t)L_ * D_ * D_, stream);
  cvt(W1, w1b, (size_t)L_ * DFF_ * D_, stream);
  cvt(W2, w2b, (size_t)L_ * DFF_ * D_, stream);
  cvt(qa_embed, valsb, ND, stream);

  dim3 gproj(D_ / 128, NTOK / 128);
  dim3 gf1(DFF_ / 128, NTOK / 128);
  dim3 gf2(D_ / 128, NTOK / 128);
  dim3 gtr(S_ / 64, H_, B_);
  int gattn = B_ * H_ * 8;   // 2048 blocks, 2 complementary pairs (4 waves) each

  for (int l = 0; l < L_; ++l) {
    int first = (l % 2 == 0);
    const unsigned short* vA = first ? valsb : xb;

    gemm_bt_bf16<<<gproj, 256, 0, stream>>>(xb, wkb + (size_t)l * D_ * D_, bk + l * D_,
                                            nullptr, qkb, (int)NTOK, D_, D_, 0);
    gemm_bt_bf16<<<gproj, 256, 0, stream>>>(vA, wvb + (size_t)l * D_ * D_, bv + l * D_,
                                            nullptr, vb, (int)NTOK, D_, D_, 0);
    transpose_heads_bf16<<<gtr, 256, 0, stream>>>(vb, vtb);
    attn_mfma3<<<gattn, 256, 0, stream>>>(qkb, vtb, gammas + l * H_, aob, first ? 0 : 1);
    gemm_bt_bf16<<<gproj, 256, 0, stream>>>(aob, wob + (size_t)l * D_ * D_, bo + l * D_,
                                            qkf, nullptr, (int)NTOK, D_, D_, 0);
    add_ln<<<(int)NTOK, 256, 0, stream>>>(x, xb, qkf, ln1_g + l * D_, ln1_b + l * D_);
    if (first) {
      gemm_bt_bf16<<<gf1, 256, 0, stream>>>(xb, w1b + (size_t)l * DFF_ * D_, b1 + l * DFF_,
                                            nullptr, ffnb, (int)NTOK, DFF_, D_, 1);
      gemm_bt_bf16<<<gf2, 256, 0, stream>>>(ffnb, w2b + (size_t)l * D_ * DFF_, b2 + l * D_,
                                            qkf, nullptr, (int)NTOK, D_, DFF_, 0);
      add_ln<<<(int)NTOK, 256, 0, stream>>>(x, xb, qkf, ln2_g + l * D_, ln2_b + l * D_);
    }
  }
}

// Round 18
// 1052.676 us; speedup vs baseline: 1.1787x; 1.0430x over previous
//
#include <hip/hip_runtime.h>
#include <hip/hip_bf16.h>
#include <math.h>

#define B_ 32
#define S_ 512
#define D_ 512
#define H_ 8
#define DK_ 64
#define DFF_ 2048
#define L_ 4

typedef __attribute__((ext_vector_type(8))) short bf16x8;
typedef __attribute__((ext_vector_type(4))) float f32x4;

__device__ __forceinline__ unsigned short f2bf(float x) {
  union { float f; unsigned u; } v; v.f = x;
  unsigned r = v.u + 0x7fff + ((v.u >> 16) & 1);   // round-nearest-even
  return (unsigned short)(r >> 16);
}

__device__ __forceinline__ unsigned short f2h(float x) {
  union { _Float16 h; unsigned short u; } v;
  v.h = (_Float16)x;
  return v.u;
}
__device__ __forceinline__ float h2f(unsigned short u) {
  union { _Float16 h; unsigned short u; } v;
  v.u = u;
  return (float)v.h;
}

// inclusive 16-lane prefix sum via DPP row_shr (VALU only). bound_ctrl -> 0-fill.
#define DPP_ADD_SHR(x, N)                                                       \
  {                                                                             \
    int _t = __builtin_amdgcn_update_dpp(0, __float_as_int(x), 0x110 + (N),     \
                                         0xf, 0xf, true);                       \
    (x) += __int_as_float(_t);                                                  \
  }
__device__ __forceinline__ float scan16_dpp(float x) {
  DPP_ADD_SHR(x, 1);
  DPP_ADD_SHR(x, 2);
  DPP_ADD_SHR(x, 4);
  DPP_ADD_SHR(x, 8);
  return x;
}
// broadcast lane (id|15)'s value to all lanes of each 16-lane row
__device__ __forceinline__ float bcast15(float x) {
  return __int_as_float(__builtin_amdgcn_ds_swizzle(__float_as_int(x), 0x1FF));
}

__device__ __forceinline__ void load_lds16(const void* g, void* l) {
  __builtin_amdgcn_global_load_lds(
      (const __attribute__((address_space(1))) void*)g,
      (__attribute__((address_space(3))) void*)l, 16, 0, 0);
}

// ---------- f32 -> bf16 convert ----------
__global__ __launch_bounds__(256) void cvt_f32_bf16(
    const float* __restrict__ in, unsigned short* __restrict__ out, size_t n8)
{
  size_t idx = (size_t)blockIdx.x * 256 + threadIdx.x;
  size_t stride = (size_t)gridDim.x * 256;
  for (size_t i = idx; i < n8; i += stride) {
    const float4* p = (const float4*)(in + i * 8);
    float4 a = p[0], b = p[1];
    union { unsigned short u[8]; int4 v; } o;
    o.u[0] = f2bf(a.x); o.u[1] = f2bf(a.y); o.u[2] = f2bf(a.z); o.u[3] = f2bf(a.w);
    o.u[4] = f2bf(b.x); o.u[5] = f2bf(b.y); o.u[6] = f2bf(b.z); o.u[7] = f2bf(b.w);
    *(int4*)(out + i * 8) = o.v;
  }
}

// ---------- copy f32 + emit bf16 ----------
__global__ __launch_bounds__(256) void copy_cvt(
    const float* __restrict__ in, float* __restrict__ outf,
    unsigned short* __restrict__ outb, size_t n8)
{
  size_t idx = (size_t)blockIdx.x * 256 + threadIdx.x;
  size_t stride = (size_t)gridDim.x * 256;
  for (size_t i = idx; i < n8; i += stride) {
    const float4* p = (const float4*)(in + i * 8);
    float4 a = p[0], b = p[1];
    ((float4*)(outf + i * 8))[0] = a;
    ((float4*)(outf + i * 8))[1] = b;
    union { unsigned short u[8]; int4 v; } o;
    o.u[0] = f2bf(a.x); o.u[1] = f2bf(a.y); o.u[2] = f2bf(a.z); o.u[3] = f2bf(a.w);
    o.u[4] = f2bf(b.x); o.u[5] = f2bf(b.y); o.u[6] = f2bf(b.z); o.u[7] = f2bf(b.w);
    *(int4*)(outb + i * 8) = o.v;
  }
}

// ---------- bf16 MFMA GEMM: C[M,N] = A[M,K] @ W[N,K]^T + bias ----------
// vt!=0: write Cb transposed per-head: vt[((b*H + col/64)*64 + col%64)*S + j]
// (fragment rows are 4 consecutive tokens -> contiguous j -> one int2 store).
__global__ __launch_bounds__(256) void gemm_bt_bf16(
    const unsigned short* __restrict__ A, const unsigned short* __restrict__ W,
    const float* __restrict__ bias,
    float* __restrict__ Cf, unsigned short* __restrict__ Cb,
    int M, int N, int K, int relu, int vt)
{
  __shared__ __align__(16) short As[128 * 32];
  __shared__ __align__(16) short Ws[128 * 32];
  int tid = threadIdx.x;
  int lane = tid & 63, w = tid >> 6;
  int wr = w >> 1, wc = w & 1;
  int bm = blockIdx.y * 128, bn = blockIdx.x * 128;

  f32x4 acc[4][4];
  #pragma unroll
  for (int m = 0; m < 4; ++m)
    #pragma unroll
    for (int n = 0; n < 4; ++n) acc[m][n] = (f32x4){0.f, 0.f, 0.f, 0.f};

  int srow = tid >> 2;
  int skB  = (tid & 3) * 16;
  const char* pa0 = (const char*)(A + (size_t)(bm + srow) * K) + skB;
  const char* pa1 = (const char*)(A + (size_t)(bm + 64 + srow) * K) + skB;
  const char* pw0 = (const char*)(W + (size_t)(bn + srow) * K) + skB;
  const char* pw1 = (const char*)(W + (size_t)(bn + 64 + srow) * K) + skB;
  char* lA0 = (char*)As + w * 1024;
  char* lA1 = (char*)As + 4096 + w * 1024;
  char* lW0 = (char*)Ws + w * 1024;
  char* lW1 = (char*)Ws + 4096 + w * 1024;

  int r = lane & 15, k8 = lane >> 4;
  const bf16x8* Arow = (const bf16x8*)As;
  const bf16x8* Wrow = (const bf16x8*)Ws;

  for (int k0 = 0; k0 < K; k0 += 32) {
    load_lds16(pa0, lA0);
    load_lds16(pa1, lA1);
    load_lds16(pw0, lW0);
    load_lds16(pw1, lW1);
    pa0 += 64; pa1 += 64; pw0 += 64; pw1 += 64;
    __syncthreads();
    bf16x8 aF[4], bF[4];
    #pragma unroll
    for (int m = 0; m < 4; ++m) aF[m] = Arow[(wr * 64 + m * 16 + r) * 4 + k8];
    #pragma unroll
    for (int n = 0; n < 4; ++n) bF[n] = Wrow[(wc * 64 + n * 16 + r) * 4 + k8];
    #pragma unroll
    for (int m = 0; m < 4; ++m)
      #pragma unroll
      for (int n = 0; n < 4; ++n)
        acc[m][n] = __builtin_amdgcn_mfma_f32_16x16x32_bf16(aF[m], bF[n], acc[m][n], 0, 0, 0);
    __syncthreads();
  }

  int orow0 = bm + wr * 64 + (lane >> 4) * 4;
  int ocol0 = bn + wc * 64 + (lane & 15);
  if (vt) {
    // transposed per-head store (V projection): values identical to normal path
    #pragma unroll
    for (int n = 0; n < 4; ++n) {
      int col = ocol0 + n * 16;
      float bv = bias[col];
      int hh = col >> 6, dd = col & 63;
      #pragma unroll
      for (int m = 0; m < 4; ++m) {
        int row = orow0 + m * 16;
        int bb = row >> 9;           // row / S_
        int j0 = row & (S_ - 1);
        unsigned short o0 = f2bf(acc[m][n][0] + bv);
        unsigned short o1 = f2bf(acc[m][n][1] + bv);
        unsigned short o2 = f2bf(acc[m][n][2] + bv);
        unsigned short o3 = f2bf(acc[m][n][3] + bv);
        size_t base = (((size_t)(bb * H_ + hh)) * DK_ + dd) * S_ + j0;
        *(int2*)(Cb + base) = make_int2((int)o0 | ((int)o1 << 16),
                                        (int)o2 | ((int)o3 << 16));
      }
    }
  } else {
    #pragma unroll
    for (int n = 0; n < 4; ++n) {
      int col = ocol0 + n * 16;
      float bv = bias[col];
      #pragma unroll
      for (int m = 0; m < 4; ++m) {
        int row = orow0 + m * 16;
        #pragma unroll
        for (int j = 0; j < 4; ++j) {
          float val = acc[m][n][j] + bv;
          if (relu) val = fmaxf(val, 0.f);
          size_t off = (size_t)(row + j) * N + col;
          if (Cf) Cf[off] = val; else Cb[off] = f2bf(val);
        }
      }
    }
  }
}

// ---------- MFMA attention: complementary pairs, DPP scan, XCD swizzle,
// ---------- depth-1 software pipelining in phases 1 and 3 ----------
#define PSTRIDE 40
__global__ __launch_bounds__(256) void attn_mfma3(
    const unsigned short* __restrict__ qkb,   // q==k bf16 [b][s][D]
    const unsigned short* __restrict__ vtb,   // V^T bf16 [b][h][64][S]
    const float* __restrict__ gammas,
    unsigned short* __restrict__ ao,
    int maskType)
{
  __shared__ __align__(16) unsigned short scr_all[2][33 * 16][16];  // per-pair score cache
  __shared__ __align__(16) unsigned short P_all[4][16][PSTRIDE];
  int tid = threadIdx.x;
  int lane = tid & 63, w = tid >> 6;
  int hid = blockIdx.x;
  int bid = (hid & 7) * 256 + (hid >> 3);       // XCD-chunked work id (bijective)
  int pp = bid & 7;
  int h = (bid >> 3) & (H_ - 1);
  int b = bid >> 6;
  int pairIdx = w >> 1, wp = w & 1;
  int p = pp * 2 + pairIdx;                     // 0..15
  int qt = wp ? (31 - p) : p;                   // complementary pair
  int rowbase = wp ? (p + 1) * 16 : 0;
  unsigned short (*scr)[16] = &scr_all[pairIdx][rowbase];
  unsigned short (*P_lds)[PSTRIDE] = P_all[w];
  int i0 = qt * 16;
  int c15 = lane & 15, g = lane >> 4;
  int scol = 4 * ((g + (c15 >> 2)) & 3);        // bank-swizzled scr column

  const unsigned short* qbase =
      qkb + ((size_t)(b * S_ + i0 + c15)) * D_ + h * DK_ + g * 8;
  bf16x8 aQ0 = *(const bf16x8*)(qbase);
  bf16x8 aQ1 = *(const bf16x8*)(qbase + 32);
  const unsigned short* kbase = qkb + ((size_t)b * S_) * D_ + h * DK_ + g * 8;

  float gam = gammas[h];
  float gneg = -((gam > 20.f) ? gam : log1pf(__expf(gam)));   // -softplus < 0

  // ---- phase 1: QK once (K prefetched 1 tile ahead); scores -> LDS; m1 ----
  float m1[4] = {-1e30f, -1e30f, -1e30f, -1e30f};
  {
    const unsigned short* kr0 = kbase + (size_t)c15 * D_;
    bf16x8 nK0 = *(const bf16x8*)(kr0);
    bf16x8 nK1 = *(const bf16x8*)(kr0 + 32);
    for (int kt = 0; kt <= qt; ++kt) {
      bf16x8 cK0 = nK0, cK1 = nK1;
      if (kt < qt) {
        const unsigned short* nkr = kbase + (size_t)((kt + 1) * 16 + c15) * D_;
        nK0 = *(const bf16x8*)(nkr);
        nK1 = *(const bf16x8*)(nkr + 32);
      }
      f32x4 c = (f32x4){0.f, 0.f, 0.f, 0.f};
      c = __builtin_amdgcn_mfma_f32_16x16x32_bf16(aQ0, cK0, c, 0, 0, 0);
      c = __builtin_amdgcn_mfma_f32_16x16x32_bf16(aQ1, cK1, c, 0, 0, 0);
      #pragma unroll
      for (int r = 0; r < 4; ++r) c[r] *= 0.125f;
      if (kt == qt) {
        int j = kt * 16 + c15;
        #pragma unroll
        for (int r = 0; r < 4; ++r) {
          int i = i0 + 4 * g + r;
          bool valid = maskType ? (j <= i) : (j < i);
          if (!valid) c[r] = -1e30f;
        }
      }
      int j = kt * 16 + c15;
      int lo = (int)f2h(c[0]) | ((int)f2h(c[1]) << 16);
      int hi = (int)f2h(c[2]) | ((int)f2h(c[3]) << 16);
      *(int2*)&scr[j][scol] = make_int2(lo, hi);
      #pragma unroll
      for (int r = 0; r < 4; ++r) m1[r] = fmaxf(m1[r], c[r]);
    }
  }
  #pragma unroll
  for (int r = 0; r < 4; ++r)
    #pragma unroll
    for (int off = 1; off < 16; off <<= 1)
      m1[r] = fmaxf(m1[r], __shfl_xor(m1[r], off, 64));

  // ---- phase 2: sum1 from LDS scores (fixed m1) ----
  float sum1[4] = {0.f, 0.f, 0.f, 0.f};
  for (int kt = 0; kt <= qt; ++kt) {
    int j = kt * 16 + c15;
    int2 d = *(const int2*)&scr[j][scol];
    float s0 = h2f((unsigned short)(d.x & 0xffff));
    float s1 = h2f((unsigned short)((unsigned)d.x >> 16));
    float s2_ = h2f((unsigned short)(d.y & 0xffff));
    float s3 = h2f((unsigned short)((unsigned)d.y >> 16));
    sum1[0] += __expf(s0 - m1[0]);
    sum1[1] += __expf(s1 - m1[1]);
    sum1[2] += __expf(s2_ - m1[2]);
    sum1[3] += __expf(s3 - m1[3]);
  }
  #pragma unroll
  for (int r = 0; r < 4; ++r)
    #pragma unroll
    for (int off = 1; off < 16; off <<= 1)
      sum1[r] += __shfl_xor(sum1[r], off, 64);
  float inv1[4], m2b[4];
  #pragma unroll
  for (int r = 0; r < 4; ++r) {
    inv1[r] = (sum1[r] > 0.f) ? 1.f / sum1[r] : 0.f;
    m2b[r] = fmaxf(m1[r], 0.f);
  }

  // ---- phase 3: pipelined windows (scr + V prefetched 1 window ahead) ----
  f32x4 acc[4];
  #pragma unroll
  for (int dt = 0; dt < 4; ++dt) acc[dt] = (f32x4){0.f, 0.f, 0.f, 0.f};
  float sum2[4] = {0.f, 0.f, 0.f, 0.f};
  {
    float carry[4] = {0.f, 0.f, 0.f, 0.f};
    const unsigned short* vbase =
        vtb + (((size_t)(b * H_ + h) * DK_) + c15) * S_ + g * 8;
    int nwin = (qt >> 1) + 1;

    // prefetch window 0 (rows clamped to valid range; garbage discarded)
    int rB = (1 <= qt ? 1 : qt);
    int2 dA = *(const int2*)&scr[c15][scol];
    int2 dB = *(const int2*)&scr[rB * 16 + c15][scol];
    bf16x8 nV0 = *(const bf16x8*)(vbase);
    bf16x8 nV1 = *(const bf16x8*)(vbase + 16 * S_);
    bf16x8 nV2 = *(const bf16x8*)(vbase + 32 * S_);
    bf16x8 nV3 = *(const bf16x8*)(vbase + 48 * S_);

    for (int jc = 0; jc < nwin; ++jc) {
      int2 cdA = dA, cdB = dB;
      bf16x8 cV0 = nV0, cV1 = nV1, cV2 = nV2, cV3 = nV3;
      if (jc + 1 < nwin) {
        int ktA = (jc + 1) * 2;
        int ktB = (ktA + 1 <= qt) ? (ktA + 1) : qt;
        dA = *(const int2*)&scr[ktA * 16 + c15][scol];
        dB = *(const int2*)&scr[ktB * 16 + c15][scol];
        const unsigned short* vrn = vbase + (size_t)(jc + 1) * 32;
        nV0 = *(const bf16x8*)(vrn);
        nV1 = *(const bf16x8*)(vrn + 16 * S_);
        nV2 = *(const bf16x8*)(vrn + 32 * S_);
        nV3 = *(const bf16x8*)(vrn + 48 * S_);
      }
      // t2 = 0: kt = 2*jc (always valid within nwin)
      {
        int kt = jc * 2;
        float sv[4];
        sv[0] = h2f((unsigned short)(cdA.x & 0xffff));
        sv[1] = h2f((unsigned short)((unsigned)cdA.x >> 16));
        sv[2] = h2f((unsigned short)(cdA.y & 0xffff));
        sv[3] = h2f((unsigned short)((unsigned)cdA.y >> 16));
        #pragma unroll
        for (int r = 0; r < 4; ++r) {
          float e = __expf(sv[r] - m1[r]);
          float p2 = scan16_dpp(e);
          float tot = bcast15(p2);
          float cum = carry[r] + p2;
          carry[r] += tot;
          float suffix = sum1[r] - cum;
          int i = i0 + 4 * g + r;
          float pos = fabsf((float)(kt * 16 + c15 - i));
          float dist = sqrtf(fmaxf(suffix * inv1[r] * pos, 0.f));
          float te = fminf(fmaxf(__expf(dist * gneg), 1e-5f), 1e5f);
          float s2 = sv[r] * te;
          float e2 = __expf(s2 - m2b[r]);
          sum2[r] += e2;
          P_lds[4 * g + r][c15] = f2bf(e2);
        }
      }
      // t2 = 1: kt = 2*jc + 1 (may exceed qt)
      {
        int kt = jc * 2 + 1;
        if (kt <= qt) {
          float sv[4];
          sv[0] = h2f((unsigned short)(cdB.x & 0xffff));
          sv[1] = h2f((unsigned short)((unsigned)cdB.x >> 16));
          sv[2] = h2f((unsigned short)(cdB.y & 0xffff));
          sv[3] = h2f((unsigned short)((unsigned)cdB.y >> 16));
          #pragma unroll
          for (int r = 0; r < 4; ++r) {
            float e = __expf(sv[r] - m1[r]);
            float p2 = scan16_dpp(e);
            float tot = bcast15(p2);
            float cum = carry[r] + p2;
            carry[r] += tot;
            float suffix = sum1[r] - cum;
            int i = i0 + 4 * g + r;
            float pos = fabsf((float)(kt * 16 + c15 - i));
            float dist = sqrtf(fmaxf(suffix * inv1[r] * pos, 0.f));
            float te = fminf(fmaxf(__expf(dist * gneg), 1e-5f), 1e5f);
            float s2 = sv[r] * te;
            float e2 = __expf(s2 - m2b[r]);
            sum2[r] += e2;
            P_lds[4 * g + r][16 + c15] = f2bf(e2);
          }
        } else {
          #pragma unroll
          for (int r = 0; r < 4; ++r) P_lds[4 * g + r][16 + c15] = 0;
        }
      }
      // P exchange + PV MFMA (same-wave LDS; compiler orders + inserts lgkmcnt)
      bf16x8 aP = *(const bf16x8*)&P_lds[c15][g * 8];
      acc[0] = __builtin_amdgcn_mfma_f32_16x16x32_bf16(aP, cV0, acc[0], 0, 0, 0);
      acc[1] = __builtin_amdgcn_mfma_f32_16x16x32_bf16(aP, cV1, acc[1], 0, 0, 0);
      acc[2] = __builtin_amdgcn_mfma_f32_16x16x32_bf16(aP, cV2, acc[2], 0, 0, 0);
      acc[3] = __builtin_amdgcn_mfma_f32_16x16x32_bf16(aP, cV3, acc[3], 0, 0, 0);
    }
  }
  #pragma unroll
  for (int r = 0; r < 4; ++r)
    #pragma unroll
    for (int off = 1; off < 16; off <<= 1)
      sum2[r] += __shfl_xor(sum2[r], off, 64);

  // ---- epilogue: normalize (guarded), zeroPad row0, store bf16 ----
  int zp = (maskType == 0 && qt == 0);
  #pragma unroll
  for (int dt = 0; dt < 4; ++dt) {
    #pragma unroll
    for (int r = 0; r < 4; ++r) {
      int i = i0 + 4 * g + r;
      float ns = (sum2[r] > 0.f) ? 1.f / sum2[r] : 0.f;
      float val = acc[dt][r] * ns;
      if (zp && (4 * g + r) == 0) val = 0.f;
      ao[((size_t)(b * S_ + i)) * D_ + h * DK_ + dt * 16 + c15] = f2bf(val);
    }
  }
}

// ---------- wave/block reduce + residual LN (also emits bf16 x) ----------
__device__ __forceinline__ float blockReduceSum256(float v, float* red) {
  #pragma unroll
  for (int off = 32; off > 0; off >>= 1) v += __shfl_down(v, off, 64);
  int lane = threadIdx.x & 63, wid = threadIdx.x >> 6;
  __syncthreads();
  if (lane == 0) red[wid] = v;
  __syncthreads();
  return red[0] + red[1] + red[2] + red[3];
}

__global__ __launch_bounds__(256) void add_ln(
    float* __restrict__ x, unsigned short* __restrict__ xb,
    const float* __restrict__ r,
    const float* __restrict__ g, const float* __restrict__ b)
{
  int row = blockIdx.x;
  int t = threadIdx.x;
  float* xr = x + (size_t)row * D_;
  unsigned short* xbr = xb + (size_t)row * D_;
  const float* rr = r + (size_t)row * D_;
  float v0 = xr[t] + rr[t];
  float v1 = xr[t + 256] + rr[t + 256];
  __shared__ float red[4];
  float s = blockReduceSum256(v0 + v1, red);
  float mu = s * (1.0f / 512.0f);
  float d0 = v0 - mu, d1 = v1 - mu;
  float sq = blockReduceSum256(d0 * d0 + d1 * d1, red);
  float rstd = rsqrtf(sq * (1.0f / 512.0f) + 1e-5f);
  float o0 = d0 * rstd * g[t] + b[t];
  float o1 = d1 * rstd * g[t + 256] + b[t + 256];
  xr[t] = o0;
  xr[t + 256] = o1;
  xbr[t] = f2bf(o0);
  xbr[t + 256] = f2bf(o1);
}

static inline void cvt(const float* in, unsigned short* out, size_t n, hipStream_t s) {
  size_t n8 = n / 8;
  int blocks = (int)((n8 + 255) / 256);
  if (blocks > 2048) blocks = 2048;
  cvt_f32_bf16<<<blocks, 256, 0, s>>>(in, out, n8);
}

extern "C" void kernel_launch(void* const* d_in, const int* in_sizes, int n_in,
                              void* d_out, int out_size, void* d_ws, size_t ws_size,
                              hipStream_t stream) {
  const float* q_embed  = (const float*)d_in[0];
  const float* qa_embed = (const float*)d_in[1];
  const float* Wk = (const float*)d_in[2];
  const float* bk = (const float*)d_in[3];
  const float* Wv = (const float*)d_in[4];
  const float* bv = (const float*)d_in[5];
  const float* Wo = (const float*)d_in[6];
  const float* bo = (const float*)d_in[7];
  const float* gammas = (const float*)d_in[8];
  const float* ln1_g = (const float*)d_in[9];
  const float* ln1_b = (const float*)d_in[10];
  const float* W1 = (const float*)d_in[11];
  const float* b1 = (const float*)d_in[12];
  const float* W2 = (const float*)d_in[13];
  const float* b2 = (const float*)d_in[14];
  const float* ln2_g = (const float*)d_in[15];
  const float* ln2_b = (const float*)d_in[16];

  float* x = (float*)d_out;
  const size_t NTOK = (size_t)B_ * S_;      // 16384
  const size_t ND = NTOK * D_;

  float* qkf = (float*)d_ws;                               // f32 scratch [ND]
  unsigned short* xb    = (unsigned short*)(qkf + ND);     // bf16 [ND]
  unsigned short* valsb = xb + ND;
  unsigned short* qkb   = valsb + ND;
  unsigned short* vb    = qkb + ND;        // (unused; kept for layout stability)
  unsigned short* vtb   = vb + ND;
  unsigned short* aob   = vtb + ND;
  unsigned short* wkb   = aob + ND;
  unsigned short* wvb   = wkb + (size_t)L_ * D_ * D_;
  unsigned short* wob   = wvb + (size_t)L_ * D_ * D_;
  unsigned short* w1b   = wob + (size_t)L_ * D_ * D_;
  unsigned short* w2b   = w1b + (size_t)L_ * DFF_ * D_;
  unsigned short* ffnb  = qkb;   // [NTOK*DFF] aliases qkb+vb+vtb+aob (dead in FFN phase)

  // x (f32) + xb (bf16) from q_embed in one pass
  {
    size_t n8 = ND / 8;
    copy_cvt<<<2048, 256, 0, stream>>>(q_embed, x, xb, n8);
  }

  cvt(Wk, wkb, (size_t)L_ * D_ * D_, stream);
  cvt(Wv, wvb, (size_t)L_ * D_ * D_, stream);
  cvt(Wo, wob, (size_t)L_ * D_ * D_, stream);
  cvt(W1, w1b, (size_t)L_ * DFF_ * D_, stream);
  cvt(W2, w2b, (size_t)L_ * DFF_ * D_, stream);
  cvt(qa_embed, valsb, ND, stream);

  dim3 gproj(D_ / 128, NTOK / 128);
  dim3 gf1(DFF_ / 128, NTOK / 128);
  dim3 gf2(D_ / 128, NTOK / 128);
  int gattn = B_ * H_ * 8;   // 2048 blocks, 2 complementary pairs (4 waves) each

  for (int l = 0; l < L_; ++l) {
    int first = (l % 2 == 0);
    const unsigned short* vA = first ? valsb : xb;

    gemm_bt_bf16<<<gproj, 256, 0, stream>>>(xb, wkb + (size_t)l * D_ * D_, bk + l * D_,
                                            nullptr, qkb, (int)NTOK, D_, D_, 0, 0);
    // V projection writes V^T directly (per-head transposed epilogue)
    gemm_bt_bf16<<<gproj, 256, 0, stream>>>(vA, wvb + (size_t)l * D_ * D_, bv + l * D_,
                                            nullptr, vtb, (int)NTOK, D_, D_, 0, 1);
    attn_mfma3<<<gattn, 256, 0, stream>>>(qkb, vtb, gammas + l * H_, aob, first ? 0 : 1);
    gemm_bt_bf16<<<gproj, 256, 0, stream>>>(aob, wob + (size_t)l * D_ * D_, bo + l * D_,
                                            qkf, nullptr, (int)NTOK, D_, D_, 0, 0);
    add_ln<<<(int)NTOK, 256, 0, stream>>>(x, xb, qkf, ln1_g + l * D_, ln1_b + l * D_);
    if (first) {
      gemm_bt_bf16<<<gf1, 256, 0, stream>>>(xb, w1b + (size_t)l * DFF_ * D_, b1 + l * DFF_,
                                            nullptr, ffnb, (int)NTOK, DFF_, D_, 1, 0);
      gemm_bt_bf16<<<gf2, 256, 0, stream>>>(ffnb, w2b + (size_t)l * D_ * DFF_, b2 + l * D_,
                                            qkf, nullptr, (int)NTOK, D_, DFF_, 0, 0);
      add_ln<<<(int)NTOK, 256, 0, stream>>>(x, xb, qkf, ln2_g + l * D_, ln2_b + l * D_);
    }
  }
}

// Round 19
// 1018.823 us; speedup vs baseline: 1.2178x; 1.0332x over previous
//
#include <hip/hip_runtime.h>
#include <hip/hip_bf16.h>
#include <math.h>

#define B_ 32
#define S_ 512
#define D_ 512
#define H_ 8
#define DK_ 64
#define DFF_ 2048
#define L_ 4

typedef __attribute__((ext_vector_type(8))) short bf16x8;
typedef __attribute__((ext_vector_type(4))) float f32x4;

__device__ __forceinline__ unsigned short f2bf(float x) {
  union { float f; unsigned u; } v; v.f = x;
  unsigned r = v.u + 0x7fff + ((v.u >> 16) & 1);   // round-nearest-even
  return (unsigned short)(r >> 16);
}

__device__ __forceinline__ unsigned short f2h(float x) {
  union { _Float16 h; unsigned short u; } v;
  v.h = (_Float16)x;
  return v.u;
}
__device__ __forceinline__ float h2f(unsigned short u) {
  union { _Float16 h; unsigned short u; } v;
  v.u = u;
  return (float)v.h;
}

// inclusive 16-lane prefix sum via DPP row_shr (VALU only). bound_ctrl -> 0-fill.
#define DPP_ADD_SHR(x, N)                                                       \
  {                                                                             \
    int _t = __builtin_amdgcn_update_dpp(0, __float_as_int(x), 0x110 + (N),     \
                                         0xf, 0xf, true);                       \
    (x) += __int_as_float(_t);                                                  \
  }
__device__ __forceinline__ float scan16_dpp(float x) {
  DPP_ADD_SHR(x, 1);
  DPP_ADD_SHR(x, 2);
  DPP_ADD_SHR(x, 4);
  DPP_ADD_SHR(x, 8);
  return x;
}
// broadcast lane (id|15)'s value to all lanes of each 16-lane row
__device__ __forceinline__ float bcast15(float x) {
  return __int_as_float(__builtin_amdgcn_ds_swizzle(__float_as_int(x), 0x1FF));
}

__device__ __forceinline__ void load_lds16(const void* g, void* l) {
  __builtin_amdgcn_global_load_lds(
      (const __attribute__((address_space(1))) void*)g,
      (__attribute__((address_space(3))) void*)l, 16, 0, 0);
}

// ---------- f32 -> bf16 convert ----------
__global__ __launch_bounds__(256) void cvt_f32_bf16(
    const float* __restrict__ in, unsigned short* __restrict__ out, size_t n8)
{
  size_t idx = (size_t)blockIdx.x * 256 + threadIdx.x;
  size_t stride = (size_t)gridDim.x * 256;
  for (size_t i = idx; i < n8; i += stride) {
    const float4* p = (const float4*)(in + i * 8);
    float4 a = p[0], b = p[1];
    union { unsigned short u[8]; int4 v; } o;
    o.u[0] = f2bf(a.x); o.u[1] = f2bf(a.y); o.u[2] = f2bf(a.z); o.u[3] = f2bf(a.w);
    o.u[4] = f2bf(b.x); o.u[5] = f2bf(b.y); o.u[6] = f2bf(b.z); o.u[7] = f2bf(b.w);
    *(int4*)(out + i * 8) = o.v;
  }
}

// ---------- copy f32 + emit bf16 ----------
__global__ __launch_bounds__(256) void copy_cvt(
    const float* __restrict__ in, float* __restrict__ outf,
    unsigned short* __restrict__ outb, size_t n8)
{
  size_t idx = (size_t)blockIdx.x * 256 + threadIdx.x;
  size_t stride = (size_t)gridDim.x * 256;
  for (size_t i = idx; i < n8; i += stride) {
    const float4* p = (const float4*)(in + i * 8);
    float4 a = p[0], b = p[1];
    ((float4*)(outf + i * 8))[0] = a;
    ((float4*)(outf + i * 8))[1] = b;
    union { unsigned short u[8]; int4 v; } o;
    o.u[0] = f2bf(a.x); o.u[1] = f2bf(a.y); o.u[2] = f2bf(a.z); o.u[3] = f2bf(a.w);
    o.u[4] = f2bf(b.x); o.u[5] = f2bf(b.y); o.u[6] = f2bf(b.z); o.u[7] = f2bf(b.w);
    *(int4*)(outb + i * 8) = o.v;
  }
}

// ---------- bf16 MFMA GEMM: C[M,N] = A[M,K] @ W[N,K]^T + bias ----------
// 1D grid + XCD-chunked block swizzle: each XCD gets a contiguous M-range so
// A-panels (shared by all N-tiles of a row-group) stay in that XCD's L2.
// vt!=0: write Cb transposed per-head (V projection).
__global__ __launch_bounds__(256) void gemm_bt_bf16(
    const unsigned short* __restrict__ A, const unsigned short* __restrict__ W,
    const float* __restrict__ bias,
    float* __restrict__ Cf, unsigned short* __restrict__ Cb,
    int M, int N, int K, int relu, int vt, int gx, int nblocks)
{
  __shared__ __align__(16) short As[128 * 32];
  __shared__ __align__(16) short Ws[128 * 32];
  int tid = threadIdx.x;
  int lane = tid & 63, w = tid >> 6;
  int wr = w >> 1, wc = w & 1;
  int hid = blockIdx.x;
  int chunk = nblocks >> 3;                    // nblocks % 8 == 0
  int bidw = (hid & 7) * chunk + (hid >> 3);   // bijective XCD-chunked id
  int bm = (bidw / gx) * 128, bn = (bidw % gx) * 128;

  f32x4 acc[4][4];
  #pragma unroll
  for (int m = 0; m < 4; ++m)
    #pragma unroll
    for (int n = 0; n < 4; ++n) acc[m][n] = (f32x4){0.f, 0.f, 0.f, 0.f};

  int srow = tid >> 2;
  int skB  = (tid & 3) * 16;
  const char* pa0 = (const char*)(A + (size_t)(bm + srow) * K) + skB;
  const char* pa1 = (const char*)(A + (size_t)(bm + 64 + srow) * K) + skB;
  const char* pw0 = (const char*)(W + (size_t)(bn + srow) * K) + skB;
  const char* pw1 = (const char*)(W + (size_t)(bn + 64 + srow) * K) + skB;
  char* lA0 = (char*)As + w * 1024;
  char* lA1 = (char*)As + 4096 + w * 1024;
  char* lW0 = (char*)Ws + w * 1024;
  char* lW1 = (char*)Ws + 4096 + w * 1024;

  int r = lane & 15, k8 = lane >> 4;
  const bf16x8* Arow = (const bf16x8*)As;
  const bf16x8* Wrow = (const bf16x8*)Ws;

  for (int k0 = 0; k0 < K; k0 += 32) {
    load_lds16(pa0, lA0);
    load_lds16(pa1, lA1);
    load_lds16(pw0, lW0);
    load_lds16(pw1, lW1);
    pa0 += 64; pa1 += 64; pw0 += 64; pw1 += 64;
    __syncthreads();
    bf16x8 aF[4], bF[4];
    #pragma unroll
    for (int m = 0; m < 4; ++m) aF[m] = Arow[(wr * 64 + m * 16 + r) * 4 + k8];
    #pragma unroll
    for (int n = 0; n < 4; ++n) bF[n] = Wrow[(wc * 64 + n * 16 + r) * 4 + k8];
    #pragma unroll
    for (int m = 0; m < 4; ++m)
      #pragma unroll
      for (int n = 0; n < 4; ++n)
        acc[m][n] = __builtin_amdgcn_mfma_f32_16x16x32_bf16(aF[m], bF[n], acc[m][n], 0, 0, 0);
    __syncthreads();
  }

  int orow0 = bm + wr * 64 + (lane >> 4) * 4;
  int ocol0 = bn + wc * 64 + (lane & 15);
  if (vt) {
    // transposed per-head store (V projection): values identical to normal path
    #pragma unroll
    for (int n = 0; n < 4; ++n) {
      int col = ocol0 + n * 16;
      float bv = bias[col];
      int hh = col >> 6, dd = col & 63;
      #pragma unroll
      for (int m = 0; m < 4; ++m) {
        int row = orow0 + m * 16;
        int bb = row >> 9;           // row / S_
        int j0 = row & (S_ - 1);
        unsigned short o0 = f2bf(acc[m][n][0] + bv);
        unsigned short o1 = f2bf(acc[m][n][1] + bv);
        unsigned short o2 = f2bf(acc[m][n][2] + bv);
        unsigned short o3 = f2bf(acc[m][n][3] + bv);
        size_t base = (((size_t)(bb * H_ + hh)) * DK_ + dd) * S_ + j0;
        *(int2*)(Cb + base) = make_int2((int)o0 | ((int)o1 << 16),
                                        (int)o2 | ((int)o3 << 16));
      }
    }
  } else {
    #pragma unroll
    for (int n = 0; n < 4; ++n) {
      int col = ocol0 + n * 16;
      float bv = bias[col];
      #pragma unroll
      for (int m = 0; m < 4; ++m) {
        int row = orow0 + m * 16;
        #pragma unroll
        for (int j = 0; j < 4; ++j) {
          float val = acc[m][n][j] + bv;
          if (relu) val = fmaxf(val, 0.f);
          size_t off = (size_t)(row + j) * N + col;
          if (Cf) Cf[off] = val; else Cb[off] = f2bf(val);
        }
      }
    }
  }
}

// ---------- MFMA attention: complementary pairs, DPP scan, XCD swizzle,
// ---------- depth-1 software pipelining in phases 1 and 3 ----------
#define PSTRIDE 40
__global__ __launch_bounds__(256) void attn_mfma3(
    const unsigned short* __restrict__ qkb,   // q==k bf16 [b][s][D]
    const unsigned short* __restrict__ vtb,   // V^T bf16 [b][h][64][S]
    const float* __restrict__ gammas,
    unsigned short* __restrict__ ao,
    int maskType)
{
  __shared__ __align__(16) unsigned short scr_all[2][33 * 16][16];  // per-pair score cache
  __shared__ __align__(16) unsigned short P_all[4][16][PSTRIDE];
  int tid = threadIdx.x;
  int lane = tid & 63, w = tid >> 6;
  int hid = blockIdx.x;
  int bid = (hid & 7) * 256 + (hid >> 3);       // XCD-chunked work id (bijective)
  int pp = bid & 7;
  int h = (bid >> 3) & (H_ - 1);
  int b = bid >> 6;
  int pairIdx = w >> 1, wp = w & 1;
  int p = pp * 2 + pairIdx;                     // 0..15
  int qt = wp ? (31 - p) : p;                   // complementary pair
  int rowbase = wp ? (p + 1) * 16 : 0;
  unsigned short (*scr)[16] = &scr_all[pairIdx][rowbase];
  unsigned short (*P_lds)[PSTRIDE] = P_all[w];
  int i0 = qt * 16;
  int c15 = lane & 15, g = lane >> 4;
  int scol = 4 * ((g + (c15 >> 2)) & 3);        // bank-swizzled scr column

  const unsigned short* qbase =
      qkb + ((size_t)(b * S_ + i0 + c15)) * D_ + h * DK_ + g * 8;
  bf16x8 aQ0 = *(const bf16x8*)(qbase);
  bf16x8 aQ1 = *(const bf16x8*)(qbase + 32);
  const unsigned short* kbase = qkb + ((size_t)b * S_) * D_ + h * DK_ + g * 8;

  float gam = gammas[h];
  float gneg = -((gam > 20.f) ? gam : log1pf(__expf(gam)));   // -softplus < 0

  // ---- phase 1: QK once (K prefetched 1 tile ahead); scores -> LDS; m1 ----
  float m1[4] = {-1e30f, -1e30f, -1e30f, -1e30f};
  {
    const unsigned short* kr0 = kbase + (size_t)c15 * D_;
    bf16x8 nK0 = *(const bf16x8*)(kr0);
    bf16x8 nK1 = *(const bf16x8*)(kr0 + 32);
    for (int kt = 0; kt <= qt; ++kt) {
      bf16x8 cK0 = nK0, cK1 = nK1;
      if (kt < qt) {
        const unsigned short* nkr = kbase + (size_t)((kt + 1) * 16 + c15) * D_;
        nK0 = *(const bf16x8*)(nkr);
        nK1 = *(const bf16x8*)(nkr + 32);
      }
      f32x4 c = (f32x4){0.f, 0.f, 0.f, 0.f};
      c = __builtin_amdgcn_mfma_f32_16x16x32_bf16(aQ0, cK0, c, 0, 0, 0);
      c = __builtin_amdgcn_mfma_f32_16x16x32_bf16(aQ1, cK1, c, 0, 0, 0);
      #pragma unroll
      for (int r = 0; r < 4; ++r) c[r] *= 0.125f;
      if (kt == qt) {
        int j = kt * 16 + c15;
        #pragma unroll
        for (int r = 0; r < 4; ++r) {
          int i = i0 + 4 * g + r;
          bool valid = maskType ? (j <= i) : (j < i);
          if (!valid) c[r] = -1e30f;
        }
      }
      int j = kt * 16 + c15;
      int lo = (int)f2h(c[0]) | ((int)f2h(c[1]) << 16);
      int hi = (int)f2h(c[2]) | ((int)f2h(c[3]) << 16);
      *(int2*)&scr[j][scol] = make_int2(lo, hi);
      #pragma unroll
      for (int r = 0; r < 4; ++r) m1[r] = fmaxf(m1[r], c[r]);
    }
  }
  #pragma unroll
  for (int r = 0; r < 4; ++r)
    #pragma unroll
    for (int off = 1; off < 16; off <<= 1)
      m1[r] = fmaxf(m1[r], __shfl_xor(m1[r], off, 64));

  // ---- phase 2: sum1 from LDS scores (fixed m1) ----
  float sum1[4] = {0.f, 0.f, 0.f, 0.f};
  for (int kt = 0; kt <= qt; ++kt) {
    int j = kt * 16 + c15;
    int2 d = *(const int2*)&scr[j][scol];
    float s0 = h2f((unsigned short)(d.x & 0xffff));
    float s1 = h2f((unsigned short)((unsigned)d.x >> 16));
    float s2_ = h2f((unsigned short)(d.y & 0xffff));
    float s3 = h2f((unsigned short)((unsigned)d.y >> 16));
    sum1[0] += __expf(s0 - m1[0]);
    sum1[1] += __expf(s1 - m1[1]);
    sum1[2] += __expf(s2_ - m1[2]);
    sum1[3] += __expf(s3 - m1[3]);
  }
  #pragma unroll
  for (int r = 0; r < 4; ++r)
    #pragma unroll
    for (int off = 1; off < 16; off <<= 1)
      sum1[r] += __shfl_xor(sum1[r], off, 64);
  float inv1[4], m2b[4];
  #pragma unroll
  for (int r = 0; r < 4; ++r) {
    inv1[r] = (sum1[r] > 0.f) ? 1.f / sum1[r] : 0.f;
    m2b[r] = fmaxf(m1[r], 0.f);
  }

  // ---- phase 3: pipelined windows (scr + V prefetched 1 window ahead) ----
  f32x4 acc[4];
  #pragma unroll
  for (int dt = 0; dt < 4; ++dt) acc[dt] = (f32x4){0.f, 0.f, 0.f, 0.f};
  float sum2[4] = {0.f, 0.f, 0.f, 0.f};
  {
    float carry[4] = {0.f, 0.f, 0.f, 0.f};
    const unsigned short* vbase =
        vtb + (((size_t)(b * H_ + h) * DK_) + c15) * S_ + g * 8;
    int nwin = (qt >> 1) + 1;

    // prefetch window 0 (rows clamped to valid range; garbage discarded)
    int rB = (1 <= qt ? 1 : qt);
    int2 dA = *(const int2*)&scr[c15][scol];
    int2 dB = *(const int2*)&scr[rB * 16 + c15][scol];
    bf16x8 nV0 = *(const bf16x8*)(vbase);
    bf16x8 nV1 = *(const bf16x8*)(vbase + 16 * S_);
    bf16x8 nV2 = *(const bf16x8*)(vbase + 32 * S_);
    bf16x8 nV3 = *(const bf16x8*)(vbase + 48 * S_);

    for (int jc = 0; jc < nwin; ++jc) {
      int2 cdA = dA, cdB = dB;
      bf16x8 cV0 = nV0, cV1 = nV1, cV2 = nV2, cV3 = nV3;
      if (jc + 1 < nwin) {
        int ktA = (jc + 1) * 2;
        int ktB = (ktA + 1 <= qt) ? (ktA + 1) : qt;
        dA = *(const int2*)&scr[ktA * 16 + c15][scol];
        dB = *(const int2*)&scr[ktB * 16 + c15][scol];
        const unsigned short* vrn = vbase + (size_t)(jc + 1) * 32;
        nV0 = *(const bf16x8*)(vrn);
        nV1 = *(const bf16x8*)(vrn + 16 * S_);
        nV2 = *(const bf16x8*)(vrn + 32 * S_);
        nV3 = *(const bf16x8*)(vrn + 48 * S_);
      }
      // t2 = 0: kt = 2*jc (always valid within nwin)
      {
        int kt = jc * 2;
        float sv[4];
        sv[0] = h2f((unsigned short)(cdA.x & 0xffff));
        sv[1] = h2f((unsigned short)((unsigned)cdA.x >> 16));
        sv[2] = h2f((unsigned short)(cdA.y & 0xffff));
        sv[3] = h2f((unsigned short)((unsigned)cdA.y >> 16));
        #pragma unroll
        for (int r = 0; r < 4; ++r) {
          float e = __expf(sv[r] - m1[r]);
          float p2 = scan16_dpp(e);
          float tot = bcast15(p2);
          float cum = carry[r] + p2;
          carry[r] += tot;
          float suffix = sum1[r] - cum;
          int i = i0 + 4 * g + r;
          float pos = fabsf((float)(kt * 16 + c15 - i));
          float dist = sqrtf(fmaxf(suffix * inv1[r] * pos, 0.f));
          float te = fminf(fmaxf(__expf(dist * gneg), 1e-5f), 1e5f);
          float s2 = sv[r] * te;
          float e2 = __expf(s2 - m2b[r]);
          sum2[r] += e2;
          P_lds[4 * g + r][c15] = f2bf(e2);
        }
      }
      // t2 = 1: kt = 2*jc + 1 (may exceed qt)
      {
        int kt = jc * 2 + 1;
        if (kt <= qt) {
          float sv[4];
          sv[0] = h2f((unsigned short)(cdB.x & 0xffff));
          sv[1] = h2f((unsigned short)((unsigned)cdB.x >> 16));
          sv[2] = h2f((unsigned short)(cdB.y & 0xffff));
          sv[3] = h2f((unsigned short)((unsigned)cdB.y >> 16));
          #pragma unroll
          for (int r = 0; r < 4; ++r) {
            float e = __expf(sv[r] - m1[r]);
            float p2 = scan16_dpp(e);
            float tot = bcast15(p2);
            float cum = carry[r] + p2;
            carry[r] += tot;
            float suffix = sum1[r] - cum;
            int i = i0 + 4 * g + r;
            float pos = fabsf((float)(kt * 16 + c15 - i));
            float dist = sqrtf(fmaxf(suffix * inv1[r] * pos, 0.f));
            float te = fminf(fmaxf(__expf(dist * gneg), 1e-5f), 1e5f);
            float s2 = sv[r] * te;
            float e2 = __expf(s2 - m2b[r]);
            sum2[r] += e2;
            P_lds[4 * g + r][16 + c15] = f2bf(e2);
          }
        } else {
          #pragma unroll
          for (int r = 0; r < 4; ++r) P_lds[4 * g + r][16 + c15] = 0;
        }
      }
      // P exchange + PV MFMA (same-wave LDS; compiler orders + inserts lgkmcnt)
      bf16x8 aP = *(const bf16x8*)&P_lds[c15][g * 8];
      acc[0] = __builtin_amdgcn_mfma_f32_16x16x32_bf16(aP, cV0, acc[0], 0, 0, 0);
      acc[1] = __builtin_amdgcn_mfma_f32_16x16x32_bf16(aP, cV1, acc[1], 0, 0, 0);
      acc[2] = __builtin_amdgcn_mfma_f32_16x16x32_bf16(aP, cV2, acc[2], 0, 0, 0);
      acc[3] = __builtin_amdgcn_mfma_f32_16x16x32_bf16(aP, cV3, acc[3], 0, 0, 0);
    }
  }
  #pragma unroll
  for (int r = 0; r < 4; ++r)
    #pragma unroll
    for (int off = 1; off < 16; off <<= 1)
      sum2[r] += __shfl_xor(sum2[r], off, 64);

  // ---- epilogue: normalize (guarded), zeroPad row0, store bf16 ----
  int zp = (maskType == 0 && qt == 0);
  #pragma unroll
  for (int dt = 0; dt < 4; ++dt) {
    #pragma unroll
    for (int r = 0; r < 4; ++r) {
      int i = i0 + 4 * g + r;
      float ns = (sum2[r] > 0.f) ? 1.f / sum2[r] : 0.f;
      float val = acc[dt][r] * ns;
      if (zp && (4 * g + r) == 0) val = 0.f;
      ao[((size_t)(b * S_ + i)) * D_ + h * DK_ + dt * 16 + c15] = f2bf(val);
    }
  }
}

// ---------- wave/block reduce + residual LN (also emits bf16 x) ----------
__device__ __forceinline__ float blockReduceSum256(float v, float* red) {
  #pragma unroll
  for (int off = 32; off > 0; off >>= 1) v += __shfl_down(v, off, 64);
  int lane = threadIdx.x & 63, wid = threadIdx.x >> 6;
  __syncthreads();
  if (lane == 0) red[wid] = v;
  __syncthreads();
  return red[0] + red[1] + red[2] + red[3];
}

__global__ __launch_bounds__(256) void add_ln(
    float* __restrict__ x, unsigned short* __restrict__ xb,
    const float* __restrict__ r,
    const float* __restrict__ g, const float* __restrict__ b)
{
  int row = blockIdx.x;
  int t = threadIdx.x;
  float* xr = x + (size_t)row * D_;
  unsigned short* xbr = xb + (size_t)row * D_;
  const float* rr = r + (size_t)row * D_;
  float v0 = xr[t] + rr[t];
  float v1 = xr[t + 256] + rr[t + 256];
  __shared__ float red[4];
  float s = blockReduceSum256(v0 + v1, red);
  float mu = s * (1.0f / 512.0f);
  float d0 = v0 - mu, d1 = v1 - mu;
  float sq = blockReduceSum256(d0 * d0 + d1 * d1, red);
  float rstd = rsqrtf(sq * (1.0f / 512.0f) + 1e-5f);
  float o0 = d0 * rstd * g[t] + b[t];
  float o1 = d1 * rstd * g[t + 256] + b[t + 256];
  xr[t] = o0;
  xr[t + 256] = o1;
  xbr[t] = f2bf(o0);
  xbr[t + 256] = f2bf(o1);
}

static inline void cvt(const float* in, unsigned short* out, size_t n, hipStream_t s) {
  size_t n8 = n / 8;
  int blocks = (int)((n8 + 255) / 256);
  if (blocks > 2048) blocks = 2048;
  cvt_f32_bf16<<<blocks, 256, 0, s>>>(in, out, n8);
}

extern "C" void kernel_launch(void* const* d_in, const int* in_sizes, int n_in,
                              void* d_out, int out_size, void* d_ws, size_t ws_size,
                              hipStream_t stream) {
  const float* q_embed  = (const float*)d_in[0];
  const float* qa_embed = (const float*)d_in[1];
  const float* Wk = (const float*)d_in[2];
  const float* bk = (const float*)d_in[3];
  const float* Wv = (const float*)d_in[4];
  const float* bv = (const float*)d_in[5];
  const float* Wo = (const float*)d_in[6];
  const float* bo = (const float*)d_in[7];
  const float* gammas = (const float*)d_in[8];
  const float* ln1_g = (const float*)d_in[9];
  const float* ln1_b = (const float*)d_in[10];
  const float* W1 = (const float*)d_in[11];
  const float* b1 = (const float*)d_in[12];
  const float* W2 = (const float*)d_in[13];
  const float* b2 = (const float*)d_in[14];
  const float* ln2_g = (const float*)d_in[15];
  const float* ln2_b = (const float*)d_in[16];

  float* x = (float*)d_out;
  const size_t NTOK = (size_t)B_ * S_;      // 16384
  const size_t ND = NTOK * D_;

  float* qkf = (float*)d_ws;                               // f32 scratch [ND]
  unsigned short* xb    = (unsigned short*)(qkf + ND);     // bf16 [ND]
  unsigned short* valsb = xb + ND;
  unsigned short* qkb   = valsb + ND;
  unsigned short* vb    = qkb + ND;        // (unused; kept for layout stability)
  unsigned short* vtb   = vb + ND;
  unsigned short* aob   = vtb + ND;
  unsigned short* wkb   = aob + ND;
  unsigned short* wvb   = wkb + (size_t)L_ * D_ * D_;
  unsigned short* wob   = wvb + (size_t)L_ * D_ * D_;
  unsigned short* w1b   = wob + (size_t)L_ * D_ * D_;
  unsigned short* w2b   = w1b + (size_t)L_ * DFF_ * D_;
  unsigned short* ffnb  = qkb;   // [NTOK*DFF] aliases qkb+vb+vtb+aob (dead in FFN phase)

  // x (f32) + xb (bf16) from q_embed in one pass
  {
    size_t n8 = ND / 8;
    copy_cvt<<<2048, 256, 0, stream>>>(q_embed, x, xb, n8);
  }

  cvt(Wk, wkb, (size_t)L_ * D_ * D_, stream);
  cvt(Wv, wvb, (size_t)L_ * D_ * D_, stream);
  cvt(Wo, wob, (size_t)L_ * D_ * D_, stream);
  cvt(W1, w1b, (size_t)L_ * DFF_ * D_, stream);
  cvt(W2, w2b, (size_t)L_ * DFF_ * D_, stream);
  cvt(qa_embed, valsb, ND, stream);

  // 1D grids (all divisible by 8 for the XCD-chunked swizzle)
  int gxp = D_ / 128;                  // 4
  int nbp = gxp * (int)(NTOK / 128);   // 512
  int gx1 = DFF_ / 128;                // 16
  int nb1 = gx1 * (int)(NTOK / 128);   // 2048
  int gattn = B_ * H_ * 8;             // 2048

  for (int l = 0; l < L_; ++l) {
    int first = (l % 2 == 0);
    const unsigned short* vA = first ? valsb : xb;

    gemm_bt_bf16<<<nbp, 256, 0, stream>>>(xb, wkb + (size_t)l * D_ * D_, bk + l * D_,
                                          nullptr, qkb, (int)NTOK, D_, D_, 0, 0, gxp, nbp);
    gemm_bt_bf16<<<nbp, 256, 0, stream>>>(vA, wvb + (size_t)l * D_ * D_, bv + l * D_,
                                          nullptr, vtb, (int)NTOK, D_, D_, 0, 1, gxp, nbp);
    attn_mfma3<<<gattn, 256, 0, stream>>>(qkb, vtb, gammas + l * H_, aob, first ? 0 : 1);
    gemm_bt_bf16<<<nbp, 256, 0, stream>>>(aob, wob + (size_t)l * D_ * D_, bo + l * D_,
                                          qkf, nullptr, (int)NTOK, D_, D_, 0, 0, gxp, nbp);
    add_ln<<<(int)NTOK, 256, 0, stream>>>(x, xb, qkf, ln1_g + l * D_, ln1_b + l * D_);
    if (first) {
      gemm_bt_bf16<<<nb1, 256, 0, stream>>>(xb, w1b + (size_t)l * DFF_ * D_, b1 + l * DFF_,
                                            nullptr, ffnb, (int)NTOK, DFF_, D_, 1, 0, gx1, nb1);
      gemm_bt_bf16<<<nbp, 256, 0, stream>>>(ffnb, w2b + (size_t)l * D_ * DFF_, b2 + l * D_,
                                            qkf, nullptr, (int)NTOK, D_, DFF_, 0, 0, gxp, nbp);
      add_ln<<<(int)NTOK, 256, 0, stream>>>(x, xb, qkf, ln2_g + l * D_, ln2_b + l * D_);
    }
  }
}

// Round 20
// 1016.371 us; speedup vs baseline: 1.2208x; 1.0024x over previous
//
#include <hip/hip_runtime.h>
#include <hip/hip_bf16.h>
#include <math.h>

#define B_ 32
#define S_ 512
#define D_ 512
#define H_ 8
#define DK_ 64
#define DFF_ 2048
#define L_ 4

typedef __attribute__((ext_vector_type(8))) short bf16x8;
typedef __attribute__((ext_vector_type(4))) float f32x4;

__device__ __forceinline__ unsigned short f2bf(float x) {
  union { float f; unsigned u; } v; v.f = x;
  unsigned r = v.u + 0x7fff + ((v.u >> 16) & 1);   // round-nearest-even
  return (unsigned short)(r >> 16);
}

__device__ __forceinline__ unsigned short f2h(float x) {
  union { _Float16 h; unsigned short u; } v;
  v.h = (_Float16)x;
  return v.u;
}
__device__ __forceinline__ float h2f(unsigned short u) {
  union { _Float16 h; unsigned short u; } v;
  v.u = u;
  return (float)v.h;
}

// inclusive 16-lane prefix sum via DPP row_shr (VALU only). bound_ctrl -> 0-fill.
#define DPP_ADD_SHR(x, N)                                                       \
  {                                                                             \
    int _t = __builtin_amdgcn_update_dpp(0, __float_as_int(x), 0x110 + (N),     \
                                         0xf, 0xf, true);                       \
    (x) += __int_as_float(_t);                                                  \
  }
__device__ __forceinline__ float scan16_dpp(float x) {
  DPP_ADD_SHR(x, 1);
  DPP_ADD_SHR(x, 2);
  DPP_ADD_SHR(x, 4);
  DPP_ADD_SHR(x, 8);
  return x;
}
// broadcast lane (id|15)'s value to all lanes of each 16-lane row
__device__ __forceinline__ float bcast15(float x) {
  return __int_as_float(__builtin_amdgcn_ds_swizzle(__float_as_int(x), 0x1FF));
}

__device__ __forceinline__ void load_lds16(const void* g, void* l) {
  __builtin_amdgcn_global_load_lds(
      (const __attribute__((address_space(1))) void*)g,
      (__attribute__((address_space(3))) void*)l, 16, 0, 0);
}

// ---------- f32 -> bf16 convert ----------
__global__ __launch_bounds__(256) void cvt_f32_bf16(
    const float* __restrict__ in, unsigned short* __restrict__ out, size_t n8)
{
  size_t idx = (size_t)blockIdx.x * 256 + threadIdx.x;
  size_t stride = (size_t)gridDim.x * 256;
  for (size_t i = idx; i < n8; i += stride) {
    const float4* p = (const float4*)(in + i * 8);
    float4 a = p[0], b = p[1];
    union { unsigned short u[8]; int4 v; } o;
    o.u[0] = f2bf(a.x); o.u[1] = f2bf(a.y); o.u[2] = f2bf(a.z); o.u[3] = f2bf(a.w);
    o.u[4] = f2bf(b.x); o.u[5] = f2bf(b.y); o.u[6] = f2bf(b.z); o.u[7] = f2bf(b.w);
    *(int4*)(out + i * 8) = o.v;
  }
}

// ---------- copy f32 + emit bf16 ----------
__global__ __launch_bounds__(256) void copy_cvt(
    const float* __restrict__ in, float* __restrict__ outf,
    unsigned short* __restrict__ outb, size_t n8)
{
  size_t idx = (size_t)blockIdx.x * 256 + threadIdx.x;
  size_t stride = (size_t)gridDim.x * 256;
  for (size_t i = idx; i < n8; i += stride) {
    const float4* p = (const float4*)(in + i * 8);
    float4 a = p[0], b = p[1];
    ((float4*)(outf + i * 8))[0] = a;
    ((float4*)(outf + i * 8))[1] = b;
    union { unsigned short u[8]; int4 v; } o;
    o.u[0] = f2bf(a.x); o.u[1] = f2bf(a.y); o.u[2] = f2bf(a.z); o.u[3] = f2bf(a.w);
    o.u[4] = f2bf(b.x); o.u[5] = f2bf(b.y); o.u[6] = f2bf(b.z); o.u[7] = f2bf(b.w);
    *(int4*)(outb + i * 8) = o.v;
  }
}

// ---------- shared GEMM body: 128x128 tile, BK=32, 4 waves ----------
__device__ __forceinline__ void gemm_tile_body(
    const unsigned short* A, const unsigned short* W, int K,
    int bm, int bn, int tid, short* As, short* Ws, f32x4 (&acc)[4][4])
{
  int lane = tid & 63, w = tid >> 6;
  int wr = w >> 1, wc = w & 1;
  int srow = tid >> 2;
  int skB  = (tid & 3) * 16;
  const char* pa0 = (const char*)(A + (size_t)(bm + srow) * K) + skB;
  const char* pa1 = (const char*)(A + (size_t)(bm + 64 + srow) * K) + skB;
  const char* pw0 = (const char*)(W + (size_t)(bn + srow) * K) + skB;
  const char* pw1 = (const char*)(W + (size_t)(bn + 64 + srow) * K) + skB;
  char* lA0 = (char*)As + w * 1024;
  char* lA1 = (char*)As + 4096 + w * 1024;
  char* lW0 = (char*)Ws + w * 1024;
  char* lW1 = (char*)Ws + 4096 + w * 1024;

  int r = lane & 15, k8 = lane >> 4;
  const bf16x8* Arow = (const bf16x8*)As;
  const bf16x8* Wrow = (const bf16x8*)Ws;

  for (int k0 = 0; k0 < K; k0 += 32) {
    load_lds16(pa0, lA0);
    load_lds16(pa1, lA1);
    load_lds16(pw0, lW0);
    load_lds16(pw1, lW1);
    pa0 += 64; pa1 += 64; pw0 += 64; pw1 += 64;
    __syncthreads();
    bf16x8 aF[4], bF[4];
    #pragma unroll
    for (int m = 0; m < 4; ++m) aF[m] = Arow[(wr * 64 + m * 16 + r) * 4 + k8];
    #pragma unroll
    for (int n = 0; n < 4; ++n) bF[n] = Wrow[(wc * 64 + n * 16 + r) * 4 + k8];
    #pragma unroll
    for (int m = 0; m < 4; ++m)
      #pragma unroll
      for (int n = 0; n < 4; ++n)
        acc[m][n] = __builtin_amdgcn_mfma_f32_16x16x32_bf16(aF[m], bF[n], acc[m][n], 0, 0, 0);
    __syncthreads();
  }
}

// ---------- bf16 MFMA GEMM (single): XCD-chunked 1D grid ----------
__global__ __launch_bounds__(256) void gemm_bt_bf16(
    const unsigned short* __restrict__ A, const unsigned short* __restrict__ W,
    const float* __restrict__ bias,
    float* __restrict__ Cf, unsigned short* __restrict__ Cb,
    int M, int N, int K, int relu, int vt, int gx, int nblocks)
{
  __shared__ __align__(16) short As[128 * 32];
  __shared__ __align__(16) short Ws[128 * 32];
  int tid = threadIdx.x;
  int lane = tid & 63, w = tid >> 6;
  int wr = w >> 1, wc = w & 1;
  int hid = blockIdx.x;
  int chunk = nblocks >> 3;                    // nblocks % 8 == 0
  int bidw = (hid & 7) * chunk + (hid >> 3);   // bijective XCD-chunked id
  int bm = (bidw / gx) * 128, bn = (bidw % gx) * 128;

  f32x4 acc[4][4];
  #pragma unroll
  for (int m = 0; m < 4; ++m)
    #pragma unroll
    for (int n = 0; n < 4; ++n) acc[m][n] = (f32x4){0.f, 0.f, 0.f, 0.f};

  gemm_tile_body(A, W, K, bm, bn, tid, As, Ws, acc);

  int orow0 = bm + wr * 64 + (lane >> 4) * 4;
  int ocol0 = bn + wc * 64 + (lane & 15);
  if (vt) {
    #pragma unroll
    for (int n = 0; n < 4; ++n) {
      int col = ocol0 + n * 16;
      float bv = bias[col];
      int hh = col >> 6, dd = col & 63;
      #pragma unroll
      for (int m = 0; m < 4; ++m) {
        int row = orow0 + m * 16;
        int bb = row >> 9;
        int j0 = row & (S_ - 1);
        unsigned short o0 = f2bf(acc[m][n][0] + bv);
        unsigned short o1 = f2bf(acc[m][n][1] + bv);
        unsigned short o2 = f2bf(acc[m][n][2] + bv);
        unsigned short o3 = f2bf(acc[m][n][3] + bv);
        size_t base = (((size_t)(bb * H_ + hh)) * DK_ + dd) * S_ + j0;
        *(int2*)(Cb + base) = make_int2((int)o0 | ((int)o1 << 16),
                                        (int)o2 | ((int)o3 << 16));
      }
    }
  } else {
    #pragma unroll
    for (int n = 0; n < 4; ++n) {
      int col = ocol0 + n * 16;
      float bv = bias[col];
      #pragma unroll
      for (int m = 0; m < 4; ++m) {
        int row = orow0 + m * 16;
        #pragma unroll
        for (int j = 0; j < 4; ++j) {
          float val = acc[m][n][j] + bv;
          if (relu) val = fmaxf(val, 0.f);
          size_t off = (size_t)(row + j) * N + col;
          if (Cf) Cf[off] = val; else Cb[off] = f2bf(val);
        }
      }
    }
  }
}

// ---------- DUAL proj GEMM: K-proj (normal store) + V-proj (V^T store) in one
// launch. Halves are independent; doubles blocks/CU for the proj phase. ----------
__global__ __launch_bounds__(256) void gemm_dual_proj(
    const unsigned short* __restrict__ A1, const unsigned short* __restrict__ W1p,
    const float* __restrict__ bias1, unsigned short* __restrict__ out1,   // qkb
    const unsigned short* __restrict__ A2, const unsigned short* __restrict__ W2p,
    const float* __restrict__ bias2, unsigned short* __restrict__ out2,   // vtb
    int K, int gx, int half)
{
  __shared__ __align__(16) short As[128 * 32];
  __shared__ __align__(16) short Ws[128 * 32];
  int tid = threadIdx.x;
  int lane = tid & 63, w = tid >> 6;
  int wr = w >> 1, wc = w & 1;
  int hid = blockIdx.x;
  int which = (hid >= half);
  int h2 = which ? (hid - half) : hid;
  int chunk = half >> 3;
  int bidw = (h2 & 7) * chunk + (h2 >> 3);
  int bm = (bidw / gx) * 128, bn = (bidw % gx) * 128;

  const unsigned short* A = which ? A2 : A1;
  const unsigned short* W = which ? W2p : W1p;
  const float* bias = which ? bias2 : bias1;

  f32x4 acc[4][4];
  #pragma unroll
  for (int m = 0; m < 4; ++m)
    #pragma unroll
    for (int n = 0; n < 4; ++n) acc[m][n] = (f32x4){0.f, 0.f, 0.f, 0.f};

  gemm_tile_body(A, W, K, bm, bn, tid, As, Ws, acc);

  int orow0 = bm + wr * 64 + (lane >> 4) * 4;
  int ocol0 = bn + wc * 64 + (lane & 15);
  if (which) {
    // V^T per-head store (R18-proven)
    #pragma unroll
    for (int n = 0; n < 4; ++n) {
      int col = ocol0 + n * 16;
      float bv = bias[col];
      int hh = col >> 6, dd = col & 63;
      #pragma unroll
      for (int m = 0; m < 4; ++m) {
        int row = orow0 + m * 16;
        int bb = row >> 9;
        int j0 = row & (S_ - 1);
        unsigned short o0 = f2bf(acc[m][n][0] + bv);
        unsigned short o1 = f2bf(acc[m][n][1] + bv);
        unsigned short o2 = f2bf(acc[m][n][2] + bv);
        unsigned short o3 = f2bf(acc[m][n][3] + bv);
        size_t base = (((size_t)(bb * H_ + hh)) * DK_ + dd) * S_ + j0;
        *(int2*)(out2 + base) = make_int2((int)o0 | ((int)o1 << 16),
                                          (int)o2 | ((int)o3 << 16));
      }
    }
  } else {
    #pragma unroll
    for (int n = 0; n < 4; ++n) {
      int col = ocol0 + n * 16;
      float bv = bias[col];
      #pragma unroll
      for (int m = 0; m < 4; ++m) {
        int row = orow0 + m * 16;
        #pragma unroll
        for (int j = 0; j < 4; ++j) {
          float val = acc[m][n][j] + bv;
          out1[(size_t)(row + j) * D_ + col] = f2bf(val);
        }
      }
    }
  }
}

// ---------- MFMA attention: complementary pairs, DPP scan, XCD swizzle,
// ---------- depth-1 software pipelining in phases 1 and 3 ----------
#define PSTRIDE 40
__global__ __launch_bounds__(256) void attn_mfma3(
    const unsigned short* __restrict__ qkb,   // q==k bf16 [b][s][D]
    const unsigned short* __restrict__ vtb,   // V^T bf16 [b][h][64][S]
    const float* __restrict__ gammas,
    unsigned short* __restrict__ ao,
    int maskType)
{
  __shared__ __align__(16) unsigned short scr_all[2][33 * 16][16];  // per-pair score cache
  __shared__ __align__(16) unsigned short P_all[4][16][PSTRIDE];
  int tid = threadIdx.x;
  int lane = tid & 63, w = tid >> 6;
  int hid = blockIdx.x;
  int bid = (hid & 7) * 256 + (hid >> 3);       // XCD-chunked work id (bijective)
  int pp = bid & 7;
  int h = (bid >> 3) & (H_ - 1);
  int b = bid >> 6;
  int pairIdx = w >> 1, wp = w & 1;
  int p = pp * 2 + pairIdx;                     // 0..15
  int qt = wp ? (31 - p) : p;                   // complementary pair
  int rowbase = wp ? (p + 1) * 16 : 0;
  unsigned short (*scr)[16] = &scr_all[pairIdx][rowbase];
  unsigned short (*P_lds)[PSTRIDE] = P_all[w];
  int i0 = qt * 16;
  int c15 = lane & 15, g = lane >> 4;
  int scol = 4 * ((g + (c15 >> 2)) & 3);        // bank-swizzled scr column

  const unsigned short* qbase =
      qkb + ((size_t)(b * S_ + i0 + c15)) * D_ + h * DK_ + g * 8;
  bf16x8 aQ0 = *(const bf16x8*)(qbase);
  bf16x8 aQ1 = *(const bf16x8*)(qbase + 32);
  const unsigned short* kbase = qkb + ((size_t)b * S_) * D_ + h * DK_ + g * 8;

  float gam = gammas[h];
  float gneg = -((gam > 20.f) ? gam : log1pf(__expf(gam)));   // -softplus < 0

  // ---- phase 1: QK once (K prefetched 1 tile ahead); scores -> LDS; m1 ----
  float m1[4] = {-1e30f, -1e30f, -1e30f, -1e30f};
  {
    const unsigned short* kr0 = kbase + (size_t)c15 * D_;
    bf16x8 nK0 = *(const bf16x8*)(kr0);
    bf16x8 nK1 = *(const bf16x8*)(kr0 + 32);
    for (int kt = 0; kt <= qt; ++kt) {
      bf16x8 cK0 = nK0, cK1 = nK1;
      if (kt < qt) {
        const unsigned short* nkr = kbase + (size_t)((kt + 1) * 16 + c15) * D_;
        nK0 = *(const bf16x8*)(nkr);
        nK1 = *(const bf16x8*)(nkr + 32);
      }
      f32x4 c = (f32x4){0.f, 0.f, 0.f, 0.f};
      c = __builtin_amdgcn_mfma_f32_16x16x32_bf16(aQ0, cK0, c, 0, 0, 0);
      c = __builtin_amdgcn_mfma_f32_16x16x32_bf16(aQ1, cK1, c, 0, 0, 0);
      #pragma unroll
      for (int r = 0; r < 4; ++r) c[r] *= 0.125f;
      if (kt == qt) {
        int j = kt * 16 + c15;
        #pragma unroll
        for (int r = 0; r < 4; ++r) {
          int i = i0 + 4 * g + r;
          bool valid = maskType ? (j <= i) : (j < i);
          if (!valid) c[r] = -1e30f;
        }
      }
      int j = kt * 16 + c15;
      int lo = (int)f2h(c[0]) | ((int)f2h(c[1]) << 16);
      int hi = (int)f2h(c[2]) | ((int)f2h(c[3]) << 16);
      *(int2*)&scr[j][scol] = make_int2(lo, hi);
      #pragma unroll
      for (int r = 0; r < 4; ++r) m1[r] = fmaxf(m1[r], c[r]);
    }
  }
  #pragma unroll
  for (int r = 0; r < 4; ++r)
    #pragma unroll
    for (int off = 1; off < 16; off <<= 1)
      m1[r] = fmaxf(m1[r], __shfl_xor(m1[r], off, 64));

  // ---- phase 2: sum1 from LDS scores (fixed m1) ----
  float sum1[4] = {0.f, 0.f, 0.f, 0.f};
  for (int kt = 0; kt <= qt; ++kt) {
    int j = kt * 16 + c15;
    int2 d = *(const int2*)&scr[j][scol];
    float s0 = h2f((unsigned short)(d.x & 0xffff));
    float s1 = h2f((unsigned short)((unsigned)d.x >> 16));
    float s2_ = h2f((unsigned short)(d.y & 0xffff));
    float s3 = h2f((unsigned short)((unsigned)d.y >> 16));
    sum1[0] += __expf(s0 - m1[0]);
    sum1[1] += __expf(s1 - m1[1]);
    sum1[2] += __expf(s2_ - m1[2]);
    sum1[3] += __expf(s3 - m1[3]);
  }
  #pragma unroll
  for (int r = 0; r < 4; ++r)
    #pragma unroll
    for (int off = 1; off < 16; off <<= 1)
      sum1[r] += __shfl_xor(sum1[r], off, 64);
  float inv1[4], m2b[4];
  #pragma unroll
  for (int r = 0; r < 4; ++r) {
    inv1[r] = (sum1[r] > 0.f) ? 1.f / sum1[r] : 0.f;
    m2b[r] = fmaxf(m1[r], 0.f);
  }

  // ---- phase 3: pipelined windows (scr + V prefetched 1 window ahead) ----
  f32x4 acc[4];
  #pragma unroll
  for (int dt = 0; dt < 4; ++dt) acc[dt] = (f32x4){0.f, 0.f, 0.f, 0.f};
  float sum2[4] = {0.f, 0.f, 0.f, 0.f};
  {
    float carry[4] = {0.f, 0.f, 0.f, 0.f};
    const unsigned short* vbase =
        vtb + (((size_t)(b * H_ + h) * DK_) + c15) * S_ + g * 8;
    int nwin = (qt >> 1) + 1;

    int rB = (1 <= qt ? 1 : qt);
    int2 dA = *(const int2*)&scr[c15][scol];
    int2 dB = *(const int2*)&scr[rB * 16 + c15][scol];
    bf16x8 nV0 = *(const bf16x8*)(vbase);
    bf16x8 nV1 = *(const bf16x8*)(vbase + 16 * S_);
    bf16x8 nV2 = *(const bf16x8*)(vbase + 32 * S_);
    bf16x8 nV3 = *(const bf16x8*)(vbase + 48 * S_);

    for (int jc = 0; jc < nwin; ++jc) {
      int2 cdA = dA, cdB = dB;
      bf16x8 cV0 = nV0, cV1 = nV1, cV2 = nV2, cV3 = nV3;
      if (jc + 1 < nwin) {
        int ktA = (jc + 1) * 2;
        int ktB = (ktA + 1 <= qt) ? (ktA + 1) : qt;
        dA = *(const int2*)&scr[ktA * 16 + c15][scol];
        dB = *(const int2*)&scr[ktB * 16 + c15][scol];
        const unsigned short* vrn = vbase + (size_t)(jc + 1) * 32;
        nV0 = *(const bf16x8*)(vrn);
        nV1 = *(const bf16x8*)(vrn + 16 * S_);
        nV2 = *(const bf16x8*)(vrn + 32 * S_);
        nV3 = *(const bf16x8*)(vrn + 48 * S_);
      }
      // t2 = 0: kt = 2*jc
      {
        int kt = jc * 2;
        float sv[4];
        sv[0] = h2f((unsigned short)(cdA.x & 0xffff));
        sv[1] = h2f((unsigned short)((unsigned)cdA.x >> 16));
        sv[2] = h2f((unsigned short)(cdA.y & 0xffff));
        sv[3] = h2f((unsigned short)((unsigned)cdA.y >> 16));
        #pragma unroll
        for (int r = 0; r < 4; ++r) {
          float e = __expf(sv[r] - m1[r]);
          float p2 = scan16_dpp(e);
          float tot = bcast15(p2);
          float cum = carry[r] + p2;
          carry[r] += tot;
          float suffix = sum1[r] - cum;
          int i = i0 + 4 * g + r;
          float pos = fabsf((float)(kt * 16 + c15 - i));
          float dist = sqrtf(fmaxf(suffix * inv1[r] * pos, 0.f));
          float te = fminf(fmaxf(__expf(dist * gneg), 1e-5f), 1e5f);
          float s2 = sv[r] * te;
          float e2 = __expf(s2 - m2b[r]);
          sum2[r] += e2;
          P_lds[4 * g + r][c15] = f2bf(e2);
        }
      }
      // t2 = 1: kt = 2*jc + 1
      {
        int kt = jc * 2 + 1;
        if (kt <= qt) {
          float sv[4];
          sv[0] = h2f((unsigned short)(cdB.x & 0xffff));
          sv[1] = h2f((unsigned short)((unsigned)cdB.x >> 16));
          sv[2] = h2f((unsigned short)(cdB.y & 0xffff));
          sv[3] = h2f((unsigned short)((unsigned)cdB.y >> 16));
          #pragma unroll
          for (int r = 0; r < 4; ++r) {
            float e = __expf(sv[r] - m1[r]);
            float p2 = scan16_dpp(e);
            float tot = bcast15(p2);
            float cum = carry[r] + p2;
            carry[r] += tot;
            float suffix = sum1[r] - cum;
            int i = i0 + 4 * g + r;
            float pos = fabsf((float)(kt * 16 + c15 - i));
            float dist = sqrtf(fmaxf(suffix * inv1[r] * pos, 0.f));
            float te = fminf(fmaxf(__expf(dist * gneg), 1e-5f), 1e5f);
            float s2 = sv[r] * te;
            float e2 = __expf(s2 - m2b[r]);
            sum2[r] += e2;
            P_lds[4 * g + r][16 + c15] = f2bf(e2);
          }
        } else {
          #pragma unroll
          for (int r = 0; r < 4; ++r) P_lds[4 * g + r][16 + c15] = 0;
        }
      }
      bf16x8 aP = *(const bf16x8*)&P_lds[c15][g * 8];
      acc[0] = __builtin_amdgcn_mfma_f32_16x16x32_bf16(aP, cV0, acc[0], 0, 0, 0);
      acc[1] = __builtin_amdgcn_mfma_f32_16x16x32_bf16(aP, cV1, acc[1], 0, 0, 0);
      acc[2] = __builtin_amdgcn_mfma_f32_16x16x32_bf16(aP, cV2, acc[2], 0, 0, 0);
      acc[3] = __builtin_amdgcn_mfma_f32_16x16x32_bf16(aP, cV3, acc[3], 0, 0, 0);
    }
  }
  #pragma unroll
  for (int r = 0; r < 4; ++r)
    #pragma unroll
    for (int off = 1; off < 16; off <<= 1)
      sum2[r] += __shfl_xor(sum2[r], off, 64);

  // ---- epilogue: normalize (guarded), zeroPad row0, store bf16 ----
  int zp = (maskType == 0 && qt == 0);
  #pragma unroll
  for (int dt = 0; dt < 4; ++dt) {
    #pragma unroll
    for (int r = 0; r < 4; ++r) {
      int i = i0 + 4 * g + r;
      float ns = (sum2[r] > 0.f) ? 1.f / sum2[r] : 0.f;
      float val = acc[dt][r] * ns;
      if (zp && (4 * g + r) == 0) val = 0.f;
      ao[((size_t)(b * S_ + i)) * D_ + h * DK_ + dt * 16 + c15] = f2bf(val);
    }
  }
}

// ---------- wave/block reduce + residual LN (also emits bf16 x) ----------
__device__ __forceinline__ float blockReduceSum256(float v, float* red) {
  #pragma unroll
  for (int off = 32; off > 0; off >>= 1) v += __shfl_down(v, off, 64);
  int lane = threadIdx.x & 63, wid = threadIdx.x >> 6;
  __syncthreads();
  if (lane == 0) red[wid] = v;
  __syncthreads();
  return red[0] + red[1] + red[2] + red[3];
}

__global__ __launch_bounds__(256) void add_ln(
    float* __restrict__ x, unsigned short* __restrict__ xb,
    const float* __restrict__ r,
    const float* __restrict__ g, const float* __restrict__ b)
{
  int row = blockIdx.x;
  int t = threadIdx.x;
  float* xr = x + (size_t)row * D_;
  unsigned short* xbr = xb + (size_t)row * D_;
  const float* rr = r + (size_t)row * D_;
  float v0 = xr[t] + rr[t];
  float v1 = xr[t + 256] + rr[t + 256];
  __shared__ float red[4];
  float s = blockReduceSum256(v0 + v1, red);
  float mu = s * (1.0f / 512.0f);
  float d0 = v0 - mu, d1 = v1 - mu;
  float sq = blockReduceSum256(d0 * d0 + d1 * d1, red);
  float rstd = rsqrtf(sq * (1.0f / 512.0f) + 1e-5f);
  float o0 = d0 * rstd * g[t] + b[t];
  float o1 = d1 * rstd * g[t + 256] + b[t + 256];
  xr[t] = o0;
  xr[t + 256] = o1;
  xbr[t] = f2bf(o0);
  xbr[t + 256] = f2bf(o1);
}

static inline void cvt(const float* in, unsigned short* out, size_t n, hipStream_t s) {
  size_t n8 = n / 8;
  int blocks = (int)((n8 + 255) / 256);
  if (blocks > 2048) blocks = 2048;
  cvt_f32_bf16<<<blocks, 256, 0, s>>>(in, out, n8);
}

extern "C" void kernel_launch(void* const* d_in, const int* in_sizes, int n_in,
                              void* d_out, int out_size, void* d_ws, size_t ws_size,
                              hipStream_t stream) {
  const float* q_embed  = (const float*)d_in[0];
  const float* qa_embed = (const float*)d_in[1];
  const float* Wk = (const float*)d_in[2];
  const float* bk = (const float*)d_in[3];
  const float* Wv = (const float*)d_in[4];
  const float* bv = (const float*)d_in[5];
  const float* Wo = (const float*)d_in[6];
  const float* bo = (const float*)d_in[7];
  const float* gammas = (const float*)d_in[8];
  const float* ln1_g = (const float*)d_in[9];
  const float* ln1_b = (const float*)d_in[10];
  const float* W1 = (const float*)d_in[11];
  const float* b1 = (const float*)d_in[12];
  const float* W2 = (const float*)d_in[13];
  const float* b2 = (const float*)d_in[14];
  const float* ln2_g = (const float*)d_in[15];
  const float* ln2_b = (const float*)d_in[16];

  float* x = (float*)d_out;
  const size_t NTOK = (size_t)B_ * S_;      // 16384
  const size_t ND = NTOK * D_;

  float* qkf = (float*)d_ws;                               // f32 scratch [ND]
  unsigned short* xb    = (unsigned short*)(qkf + ND);     // bf16 [ND]
  unsigned short* valsb = xb + ND;
  unsigned short* qkb   = valsb + ND;
  unsigned short* vb    = qkb + ND;        // (unused; kept for layout stability)
  unsigned short* vtb   = vb + ND;
  unsigned short* aob   = vtb + ND;
  unsigned short* wkb   = aob + ND;
  unsigned short* wvb   = wkb + (size_t)L_ * D_ * D_;
  unsigned short* wob   = wvb + (size_t)L_ * D_ * D_;
  unsigned short* w1b   = wob + (size_t)L_ * D_ * D_;
  unsigned short* w2b   = w1b + (size_t)L_ * DFF_ * D_;
  unsigned short* ffnb  = qkb;   // [NTOK*DFF] aliases qkb+vb+vtb+aob (dead in FFN phase)

  // x (f32) + xb (bf16) from q_embed in one pass
  {
    size_t n8 = ND / 8;
    copy_cvt<<<2048, 256, 0, stream>>>(q_embed, x, xb, n8);
  }

  cvt(Wk, wkb, (size_t)L_ * D_ * D_, stream);
  cvt(Wv, wvb, (size_t)L_ * D_ * D_, stream);
  cvt(Wo, wob, (size_t)L_ * D_ * D_, stream);
  cvt(W1, w1b, (size_t)L_ * DFF_ * D_, stream);
  cvt(W2, w2b, (size_t)L_ * DFF_ * D_, stream);
  cvt(qa_embed, valsb, ND, stream);

  // 1D grids (all divisible by 8 for the XCD-chunked swizzle)
  int gxp = D_ / 128;                  // 4
  int nbp = gxp * (int)(NTOK / 128);   // 512
  int gx1 = DFF_ / 128;                // 16
  int nb1 = gx1 * (int)(NTOK / 128);   // 2048
  int gattn = B_ * H_ * 8;             // 2048

  for (int l = 0; l < L_; ++l) {
    int first = (l % 2 == 0);
    const unsigned short* vA = first ? valsb : xb;

    // K-proj + V-proj fused into one launch (independent halves)
    gemm_dual_proj<<<2 * nbp, 256, 0, stream>>>(
        xb, wkb + (size_t)l * D_ * D_, bk + l * D_, qkb,
        vA, wvb + (size_t)l * D_ * D_, bv + l * D_, vtb,
        D_, gxp, nbp);
    attn_mfma3<<<gattn, 256, 0, stream>>>(qkb, vtb, gammas + l * H_, aob, first ? 0 : 1);
    gemm_bt_bf16<<<nbp, 256, 0, stream>>>(aob, wob + (size_t)l * D_ * D_, bo + l * D_,
                                          qkf, nullptr, (int)NTOK, D_, D_, 0, 0, gxp, nbp);
    add_ln<<<(int)NTOK, 256, 0, stream>>>(x, xb, qkf, ln1_g + l * D_, ln1_b + l * D_);
    if (first) {
      gemm_bt_bf16<<<nb1, 256, 0, stream>>>(xb, w1b + (size_t)l * DFF_ * D_, b1 + l * DFF_,
                                            nullptr, ffnb, (int)NTOK, DFF_, D_, 1, 0, gx1, nb1);
      gemm_bt_bf16<<<nbp, 256, 0, stream>>>(ffnb, w2b + (size_t)l * D_ * DFF_, b2 + l * D_,
                                            qkf, nullptr, (int)NTOK, D_, DFF_, 0, 0, gxp, nbp);
      add_ln<<<(int)NTOK, 256, 0, stream>>>(x, xb, qkf, ln2_g + l * D_, ln2_b + l * D_);
    }
  }
}